// Round 11
// baseline (310.004 us; speedup 1.0000x reference)
//
#include <hip/hip_runtime.h>

#define N_NODESC 100000
#define N_EDGESC 10000
#define N_PAIRSC 1600000
#define FDIM 128

#define NB_E 200     // edge buckets
#define EPB 50       // edges per bucket (200*50 = 10000)
#define NB_N 782     // node buckets
#define NPB 128      // nodes per bucket (782*128 = 100096 >= 100000)
#define NBINS (NB_E + NB_N)   // 982

#define ECAP 8704    // E-bucket item capacity (mean 8000, sigma 89 -> 8 sigma)
#define NCAP 2560    // N-bucket item capacity (mean 2046, sigma 45 -> 11 sigma)

#define PA_CHUNK 8192
#define PA_NCH ((N_PAIRSC + PA_CHUNK - 1) / PA_CHUNK)  // 196

#define BH_BLOCKS 250
#define BH_CHUNK 6400   // 250 * 6400 = 1.6M exactly

typedef short bf16x8 __attribute__((ext_vector_type(8)));
typedef float f32x4 __attribute__((ext_vector_type(4)));
typedef float f32x2 __attribute__((ext_vector_type(2)));
typedef int i32x4 __attribute__((ext_vector_type(4)));
typedef unsigned u32x4 __attribute__((ext_vector_type(4)));

__device__ __forceinline__ unsigned short f2b(float f) {
  unsigned u = __float_as_uint(f);
  u += 0x7fffu + ((u >> 16) & 1u);
  return (unsigned short)(u >> 16);
}
__device__ __forceinline__ float b2f(unsigned short b) {
  return __uint_as_float(((unsigned)b) << 16);
}
__device__ __forceinline__ unsigned pack2(float a, float b) {
  return (unsigned)f2b(a) | ((unsigned)f2b(b) << 16);
}
// tanh-form gelu: z*e/(e+1), e=exp(1.59576912*z*(1+0.044715 z^2)). |diff| <= ~1e-3.
__device__ __forceinline__ float gelu_fast(float z) {
  float z2 = z * z;
  float w = fmaf(0.044715f, z2, 1.0f);
  float e = __expf(1.5957691216f * z * w);
  return z * e * __builtin_amdgcn_rcpf(e + 1.0f);
}

// ---------------- prep: pure streaming bf16 convert + send/recv ----------------
__global__ __launch_bounds__(256) void k_prep(const float* __restrict__ x, const float* __restrict__ action,
                                              const float* __restrict__ wmsg, const float* __restrict__ wupd,
                                              short* __restrict__ xb, short* __restrict__ wmsgb,
                                              short* __restrict__ wupdb, float* __restrict__ send,
                                              float* __restrict__ recv) {
  int i = blockIdx.x * 256 + threadIdx.x;
  if (i < (N_NODESC * FDIM) / 4) {
    const float4 v = ((const float4*)x)[i];
    uint2 o;
    o.x = pack2(v.x, v.y);
    o.y = pack2(v.z, v.w);
    ((uint2*)xb)[i] = o;
  }
  if (i < FDIM * FDIM) {
    wmsgb[i] = (short)f2b(wmsg[i]);
    wupdb[i] = (short)f2b(wupd[i]);
  }
  if (i < N_NODESC) {
    float a0 = action[i * 3 + 0], a1 = action[i * 3 + 1], a2 = action[i * 3 + 2];
    send[i] = a0 + a2;
    recv[i] = a0 + a1;
  }
}

// ---------------- bucket histogram: per-block LDS bins -> coalesced partials ----------------
__global__ __launch_bounds__(256) void k_bhist(const int* __restrict__ pn, const int* __restrict__ pe,
                                               int* __restrict__ part) {
  __shared__ int h[NBINS];
  int t = threadIdx.x;
  for (int i = t; i < NBINS; i += 256) h[i] = 0;
  __syncthreads();
  int base = blockIdx.x * BH_CHUNK;
  for (int q = t; q < BH_CHUNK / 4; q += 256) {
    int idx = base + q * 4;
    i32x4 e4 = __builtin_nontemporal_load((const i32x4*)(pe + idx));
    i32x4 v4 = __builtin_nontemporal_load((const i32x4*)(pn + idx));
#pragma unroll
    for (int j = 0; j < 4; j++) {
      atomicAdd(&h[e4[j] / EPB], 1);
      atomicAdd(&h[NB_E + (v4[j] >> 7)], 1);
    }
  }
  __syncthreads();
  for (int i = t; i < NBINS; i += 256) part[blockIdx.x * NBINS + i] = h[i];
}

// ---------------- scan helper ----------------
__device__ __forceinline__ int wave_incl_scan(int v, int lane) {
#pragma unroll
  for (int d = 1; d < 64; d <<= 1) {
    int n = __shfl_up(v, d, 64);
    if (lane >= d) v += n;
  }
  return v;
}

// ---------------- reduce partials + scan bucket bases + init cursors ----------------
__global__ __launch_bounds__(256) void k_bscan(const int* __restrict__ part, int* __restrict__ ebase,
                                               int* __restrict__ nbase, int* __restrict__ gcure,
                                               int* __restrict__ gcurn) {
  __shared__ int tot[NBINS];
  int t = threadIdx.x;
  for (int i = t; i < NBINS; i += 256) {
    int s = 0;
    for (int b = 0; b < BH_BLOCKS; b++) s += part[b * NBINS + i];
    tot[i] = s;
  }
  __syncthreads();
  if (t < 64) {
    int carry = 0;
    for (int base = 0; base < NB_E; base += 64) {
      int idx = base + t;
      int v = (idx < NB_E) ? tot[idx] : 0;
      int inc = wave_incl_scan(v, t);
      if (idx < NB_E) { ebase[idx] = carry + inc - v; gcure[idx] = carry + inc - v; }
      carry += __shfl(inc, 63, 64);
    }
    if (t == 0) ebase[NB_E] = N_PAIRSC;
  } else if (t < 128) {
    int lane = t - 64;
    int carry = 0;
    for (int base = 0; base < NB_N; base += 64) {
      int idx = base + lane;
      int v = (idx < NB_N) ? tot[NB_E + idx] : 0;
      int inc = wave_incl_scan(v, lane);
      if (idx < NB_N) { nbase[idx] = carry + inc - v; gcurn[idx] = carry + inc - v; }
      carry += __shfl(inc, 63, 64);
    }
    if (lane == 0) nbase[NB_N] = N_PAIRSC;
  }
}

// ---------------- phase A: coarse bucket partition (31-bit packed items) ----------------
__global__ __launch_bounds__(256) void k_part(const int* __restrict__ pn, const int* __restrict__ pe,
                                              int* __restrict__ gcure, int* __restrict__ gcurn,
                                              unsigned* __restrict__ buckE,
                                              unsigned* __restrict__ buckN) {
  __shared__ int ce[NB_E], cn[NB_N];
  int t = threadIdx.x;
  for (int i = t; i < NB_E; i += 256) ce[i] = 0;
  for (int i = t; i < NB_N; i += 256) cn[i] = 0;
  __syncthreads();
  long long base = (long long)blockIdx.x * PA_CHUNK;
  for (int q = t; q < PA_CHUNK / 4; q += 256) {
    long long idx = base + (long long)q * 4;
    if (idx >= N_PAIRSC) break;
    i32x4 e4 = __builtin_nontemporal_load((const i32x4*)(pe + idx));
    i32x4 v4 = __builtin_nontemporal_load((const i32x4*)(pn + idx));
#pragma unroll
    for (int j = 0; j < 4; j++) {
      atomicAdd(&ce[e4[j] / EPB], 1);
      atomicAdd(&cn[v4[j] >> 7], 1);
    }
  }
  __syncthreads();
  for (int i = t; i < NB_E; i += 256) ce[i] = atomicAdd(&gcure[i], ce[i]);
  for (int i = t; i < NB_N; i += 256) cn[i] = atomicAdd(&gcurn[i], cn[i]);
  __syncthreads();
  for (int q = t; q < PA_CHUNK / 4; q += 256) {
    long long idx = base + (long long)q * 4;
    if (idx >= N_PAIRSC) break;
    i32x4 e4 = __builtin_nontemporal_load((const i32x4*)(pe + idx));
    i32x4 v4 = __builtin_nontemporal_load((const i32x4*)(pn + idx));
#pragma unroll
    for (int j = 0; j < 4; j++) {
      unsigned ee = (unsigned)e4[j], vv = (unsigned)v4[j];
      int p1 = atomicAdd(&ce[ee / EPB], 1);
      buckE[p1] = (ee << 17) | vv;          // edge key (14b) | node val (17b)
      int p2 = atomicAdd(&cn[vv >> 7], 1);
      buckN[p2] = (vv << 14) | ee;          // node key (17b) | edge val (14b)
    }
  }
}

// ---------------- GEMM 1: m_ji = gelu(x @ Wmsg^T) * send  -> fp8, 32 rows/wave ----------------
__global__ __launch_bounds__(256) void k_gemm_msg(const short* __restrict__ xb, const short* __restrict__ wb,
                                                  const float* __restrict__ send,
                                                  unsigned char* __restrict__ mji8) {
  int gw = (blockIdx.x * 256 + threadIdx.x) >> 6;
  int lane = threadIdx.x & 63;
  if (gw >= N_NODESC / 32) return;
  int rb = gw * 32;
  int lr = lane & 15, lg = lane >> 4;

  bf16x8 A0[4], A1[4];
  const short* xrow0 = xb + (size_t)(rb + lr) * FDIM + lg * 8;
  const short* xrow1 = xrow0 + 16 * FDIM;
#pragma unroll
  for (int kk = 0; kk < 4; kk++) {
    A0[kk] = *(const bf16x8*)(xrow0 + kk * 32);
    A1[kk] = *(const bf16x8*)(xrow1 + kk * 32);
  }

  float sv0[4], sv1[4];
#pragma unroll
  for (int j = 0; j < 4; j++) {
    sv0[j] = send[rb + lg * 4 + j];
    sv1[j] = send[rb + 16 + lg * 4 + j];
  }

#pragma unroll
  for (int c = 0; c < 8; c++) {
    f32x4 acc0 = {0.f, 0.f, 0.f, 0.f}, acc1 = {0.f, 0.f, 0.f, 0.f};
    const short* wrow = wb + (size_t)(16 * c + lr) * FDIM + lg * 8;
#pragma unroll
    for (int kk = 0; kk < 4; kk++) {
      bf16x8 B = *(const bf16x8*)(wrow + kk * 32);
      acc0 = __builtin_amdgcn_mfma_f32_16x16x32_bf16(A0[kk], B, acc0, 0, 0, 0);
      acc1 = __builtin_amdgcn_mfma_f32_16x16x32_bf16(A1[kk], B, acc1, 0, 0, 0);
    }
    int col = 16 * c + lr;
#pragma unroll
    for (int j = 0; j < 4; j++) {
      float m0 = gelu_fast(acc0[j]) * sv0[j];
      float m1 = gelu_fast(acc1[j]) * sv1[j];
      int row0 = rb + lg * 4 + j;
      mji8[(size_t)row0 * FDIM + col] =
          (unsigned char)(__builtin_amdgcn_cvt_pk_fp8_f32(m0, m0, 0, false) & 0xFF);
      mji8[(size_t)(row0 + 16) * FDIM + col] =
          (unsigned char)(__builtin_amdgcn_cvt_pk_fp8_f32(m1, m1, 0, false) & 0xFF);
    }
  }
}

// ---------------- fused E: sort bucket in LDS + per-edge gather -> efeat8 ----------------
// One block per 50-edge bucket; the sorted pair list never touches global memory.
__global__ __launch_bounds__(256) void k_edge_f(const unsigned* __restrict__ buckE,
                                                const int* __restrict__ ebase,
                                                const unsigned char* __restrict__ mji8,
                                                unsigned char* __restrict__ efeat8) {
  __shared__ int cnt_s[EPB], cur_s[EPB];
  __shared__ int list[ECAP];
  int b = blockIdx.x, t = threadIdx.x;
  int lo = b * EPB;
  int beg = ebase[b], end = ebase[b + 1];
  if (t < EPB) cnt_s[t] = 0;
  __syncthreads();
  for (int i = beg + t; i < end; i += 256)
    atomicAdd(&cnt_s[(int)(buckE[i] >> 17) - lo], 1);
  __syncthreads();
  if (t < 64) {
    int v = (t < EPB) ? cnt_s[t] : 0;
    int inc = wave_incl_scan(v, t);
    if (t < EPB) cur_s[t] = inc - v;   // block-local exclusive offset
  }
  __syncthreads();
  for (int i = beg + t; i < end; i += 256) {
    unsigned u = buckE[i];
    int key = (int)(u >> 17) - lo;
    int pos = atomicAdd(&cur_s[key], 1);
    list[pos] = (int)(u & 0x1FFFF);
  }
  __syncthreads();
  // gather: wave handles 2 edges at a time (half = lane>>5), 2-pair interleave (sub2)
  int w = t >> 6, lane = t & 63;
  int half = lane >> 5, sub2 = (lane >> 4) & 1, c4 = lane & 15;
  for (int pe2 = w; pe2 < EPB / 2; pe2 += 4) {
    int el = pe2 * 2 + half;
    int cnt = cnt_s[el];
    int bl = cur_s[el] - cnt;   // after pass2, cur_s = end -> beg = end - cnt
    f32x2 a0 = {0.f, 0.f}, a1 = {0.f, 0.f}, a2 = {0.f, 0.f}, a3 = {0.f, 0.f};
#pragma unroll 4
    for (int p = sub2; p < cnt; p += 2) {
      int node = list[bl + p];
      uint2 u = ((const uint2*)(mji8 + (size_t)node * FDIM))[c4];
      a0 += __builtin_amdgcn_cvt_pk_f32_fp8(u.x, false);
      a1 += __builtin_amdgcn_cvt_pk_f32_fp8(u.x, true);
      a2 += __builtin_amdgcn_cvt_pk_f32_fp8(u.y, false);
      a3 += __builtin_amdgcn_cvt_pk_f32_fp8(u.y, true);
    }
    a0[0] += __shfl_xor(a0[0], 16, 64); a0[1] += __shfl_xor(a0[1], 16, 64);
    a1[0] += __shfl_xor(a1[0], 16, 64); a1[1] += __shfl_xor(a1[1], 16, 64);
    a2[0] += __shfl_xor(a2[0], 16, 64); a2[1] += __shfl_xor(a2[1], 16, 64);
    a3[0] += __shfl_xor(a3[0], 16, 64); a3[1] += __shfl_xor(a3[1], 16, 64);
    if (sub2 == 0) {
      float inv = 1.0f / fmaxf((float)cnt, 1.0f);
      uint2 o;
      o.x = (unsigned)__builtin_amdgcn_cvt_pk_fp8_f32(a0[0] * inv, a0[1] * inv, 0, false);
      o.x = (unsigned)__builtin_amdgcn_cvt_pk_fp8_f32(a1[0] * inv, a1[1] * inv, (int)o.x, true);
      o.y = (unsigned)__builtin_amdgcn_cvt_pk_fp8_f32(a2[0] * inv, a2[1] * inv, 0, false);
      o.y = (unsigned)__builtin_amdgcn_cvt_pk_fp8_f32(a3[0] * inv, a3[1] * inv, (int)o.y, true);
      ((uint2*)(efeat8 + (size_t)(lo + el) * FDIM))[c4] = o;
    }
  }
}

// ---------------- fused N: sort bucket + gather -> mi in LDS + GEMM2 epilogue ----------------
// One block per 128-node bucket == one 128-row GEMM tile. se/mi never touch global memory.
#define MIS 130   // mi_s row stride (u16) - breaks LDS bank aliasing
__global__ __launch_bounds__(256) void k_upd_f(const unsigned* __restrict__ buckN,
                                               const int* __restrict__ nbase,
                                               const unsigned char* __restrict__ efeat8,
                                               const float* __restrict__ recv,
                                               const short* __restrict__ xb,
                                               const short* __restrict__ wb,
                                               const float* __restrict__ bias,
                                               float* __restrict__ out) {
  __shared__ int cnt_s[NPB], cur_s[NPB];
  __shared__ int list[NCAP];
  __shared__ unsigned short mi_s[NPB * MIS];
  int b = blockIdx.x, t = threadIdx.x;
  int lo = b * NPB;
  int beg = nbase[b], end = nbase[b + 1];
  if (t < NPB) cnt_s[t] = 0;
  __syncthreads();
  for (int i = beg + t; i < end; i += 256)
    atomicAdd(&cnt_s[(int)(buckN[i] >> 14) - lo], 1);
  __syncthreads();
  if (t < 64) {
    int carry = 0;
#pragma unroll
    for (int base = 0; base < NPB; base += 64) {
      int v = cnt_s[base + t];
      int inc = wave_incl_scan(v, t);
      cur_s[base + t] = carry + inc - v;
      carry += __shfl(inc, 63, 64);
    }
  }
  __syncthreads();
  for (int i = beg + t; i < end; i += 256) {
    unsigned u = buckN[i];
    int key = (int)(u >> 14) - lo;
    int pos = atomicAdd(&cur_s[key], 1);
    list[pos] = (int)(u & 0x3FFF);
  }
  __syncthreads();
  // gather phase: 16 subs x 8 nodes each
  {
    int subid = t >> 4, c4 = t & 15;
#pragma unroll
    for (int k = 0; k < NPB / 16; k++) {
      int nl = subid * (NPB / 16) + k;
      int node = lo + nl;
      int cnt = cnt_s[nl];
      int bl = cur_s[nl] - cnt;
      f32x2 a0 = {0.f, 0.f}, a1 = {0.f, 0.f}, a2 = {0.f, 0.f}, a3 = {0.f, 0.f};
#pragma unroll 4
      for (int p = 0; p < cnt; p++) {
        int e = list[bl + p];
        uint2 u = ((const uint2*)(efeat8 + (size_t)e * FDIM))[c4];
        a0 += __builtin_amdgcn_cvt_pk_f32_fp8(u.x, false);
        a1 += __builtin_amdgcn_cvt_pk_f32_fp8(u.x, true);
        a2 += __builtin_amdgcn_cvt_pk_f32_fp8(u.y, false);
        a3 += __builtin_amdgcn_cvt_pk_f32_fp8(u.y, true);
      }
      float s = (node < N_NODESC) ? recv[node] / fmaxf((float)cnt, 1.0f) : 0.f;
      unsigned short* mr = &mi_s[nl * MIS + c4 * 8];
      ((unsigned*)mr)[0] = pack2(a0[0] * s, a0[1] * s);
      ((unsigned*)mr)[1] = pack2(a1[0] * s, a1[1] * s);
      ((unsigned*)mr)[2] = pack2(a2[0] * s, a2[1] * s);
      ((unsigned*)mr)[3] = pack2(a3[0] * s, a3[1] * s);
    }
  }
  __syncthreads();
  // gemm phase: wave w -> rows [b*128 + w*32, +32)
  int w = t >> 6, lane = t & 63;
  int lr = lane & 15, lg = lane >> 4;
  int rbl = w * 32;          // block-local row base
  int rb = lo + rbl;         // global row base
  bf16x8 A0[4], A1[4];
  const short* xrow0 = xb + (size_t)(rb + lr) * FDIM + lg * 8;
  const short* xrow1 = xrow0 + 16 * FDIM;
#pragma unroll
  for (int kk = 0; kk < 4; kk++) {
    A0[kk] = *(const bf16x8*)(xrow0 + kk * 32);
    A1[kk] = *(const bf16x8*)(xrow1 + kk * 32);
  }
#pragma unroll
  for (int c = 0; c < 8; c++) {
    f32x4 acc0 = {0.f, 0.f, 0.f, 0.f}, acc1 = {0.f, 0.f, 0.f, 0.f};
    const short* wrow = wb + (size_t)(16 * c + lr) * FDIM + lg * 8;
#pragma unroll
    for (int kk = 0; kk < 4; kk++) {
      bf16x8 B = *(const bf16x8*)(wrow + kk * 32);
      acc0 = __builtin_amdgcn_mfma_f32_16x16x32_bf16(A0[kk], B, acc0, 0, 0, 0);
      acc1 = __builtin_amdgcn_mfma_f32_16x16x32_bf16(A1[kk], B, acc1, 0, 0, 0);
    }
    int col = 16 * c + lr;
    float bc = bias[col];
#pragma unroll
    for (int j = 0; j < 4; j++) {
      int rl0 = rbl + lg * 4 + j;
      int row0 = lo + rl0;
      float z0 = acc0[j] + bc + b2f(mi_s[rl0 * MIS + col]);
      float z1 = acc1[j] + bc + b2f(mi_s[(rl0 + 16) * MIS + col]);
      if (row0 < N_NODESC)
        __builtin_nontemporal_store(gelu_fast(z0), &out[(size_t)row0 * FDIM + col]);
      if (row0 + 16 < N_NODESC)
        __builtin_nontemporal_store(gelu_fast(z1), &out[(size_t)(row0 + 16) * FDIM + col]);
    }
  }
}

extern "C" void kernel_launch(void* const* d_in, const int* in_sizes, int n_in,
                              void* d_out, int out_size, void* d_ws, size_t ws_size,
                              hipStream_t stream) {
  const float* x = (const float*)d_in[0];
  const float* action = (const float*)d_in[1];
  const float* wmsg = (const float*)d_in[2];
  const float* wupd = (const float*)d_in[3];
  const float* bupd = (const float*)d_in[4];
  const int* pn = (const int*)d_in[5];
  const int* pe = (const int*)d_in[6];
  float* out = (float*)d_out;

  char* p = (char*)d_ws;
  auto alloc = [&](size_t bytes) -> char* {
    char* r = p;
    p += (bytes + 255) & ~(size_t)255;
    return r;
  };
  short* xb = (short*)alloc((size_t)N_NODESC * FDIM * 2);
  unsigned char* mji8 = (unsigned char*)alloc((size_t)N_NODESC * FDIM);
  unsigned char* efeat8 = (unsigned char*)alloc((size_t)N_EDGESC * FDIM);
  unsigned* buckE = (unsigned*)alloc((size_t)N_PAIRSC * 4);
  unsigned* buckN = (unsigned*)alloc((size_t)N_PAIRSC * 4);
  short* wmsgb = (short*)alloc(FDIM * FDIM * 2);
  short* wupdb = (short*)alloc(FDIM * FDIM * 2);
  float* send = (float*)alloc(N_NODESC * 4);
  float* recv = (float*)alloc(N_NODESC * 4);
  int* part = (int*)alloc((size_t)BH_BLOCKS * NBINS * 4);
  int* ebase = (int*)alloc((NB_E + 1) * 4);
  int* nbase = (int*)alloc((NB_N + 1) * 4);
  int* gcure = (int*)alloc(NB_E * 4);
  int* gcurn = (int*)alloc(NB_N * 4);

  k_prep<<<12500, 256, 0, stream>>>(x, action, wmsg, wupd, xb, wmsgb, wupdb, send, recv);
  k_bhist<<<BH_BLOCKS, 256, 0, stream>>>(pn, pe, part);
  k_bscan<<<1, 256, 0, stream>>>(part, ebase, nbase, gcure, gcurn);
  k_part<<<PA_NCH, 256, 0, stream>>>(pn, pe, gcure, gcurn, buckE, buckN);
  k_gemm_msg<<<782, 256, 0, stream>>>(xb, wmsgb, send, mji8);
  k_edge_f<<<NB_E, 256, 0, stream>>>(buckE, ebase, mji8, efeat8);
  k_upd_f<<<NB_N, 256, 0, stream>>>(buckN, nbase, efeat8, recv, xb, wupdb, bupd, out);
}

// Round 12
// 214.340 us; speedup vs baseline: 1.4463x; 1.4463x over previous
//
#include <hip/hip_runtime.h>

#define N_NODESC 100000
#define N_EDGESC 10000
#define N_PAIRSC 1600000
#define FDIM 128

#define NB 200       // buckets per path
#define EPB 50       // edges per bucket  (200*50 = 10000)
#define NPB 500      // nodes per bucket  (200*500 = 100000)
#define PA_CHUNK 8192
#define PA_NCH ((N_PAIRSC + PA_CHUNK - 1) / PA_CHUNK)  // 196

#define BH_BLOCKS 250
#define BH_CHUNK 6400   // 250 * 6400 = 1.6M exactly

typedef short bf16x8 __attribute__((ext_vector_type(8)));
typedef float f32x4 __attribute__((ext_vector_type(4)));
typedef float f32x2 __attribute__((ext_vector_type(2)));
typedef int i32x4 __attribute__((ext_vector_type(4)));
typedef unsigned u32x4 __attribute__((ext_vector_type(4)));

__device__ __forceinline__ unsigned short f2b(float f) {
  unsigned u = __float_as_uint(f);
  u += 0x7fffu + ((u >> 16) & 1u);
  return (unsigned short)(u >> 16);
}
__device__ __forceinline__ float b2f(unsigned short b) {
  return __uint_as_float(((unsigned)b) << 16);
}
__device__ __forceinline__ unsigned pack2(float a, float b) {
  return (unsigned)f2b(a) | ((unsigned)f2b(b) << 16);
}
// tanh-form gelu: z*e/(e+1), e=exp(1.59576912*z*(1+0.044715 z^2)). |diff| <= ~1e-3.
__device__ __forceinline__ float gelu_fast(float z) {
  float z2 = z * z;
  float w = fmaf(0.044715f, z2, 1.0f);
  float e = __expf(1.5957691216f * z * w);
  return z * e * __builtin_amdgcn_rcpf(e + 1.0f);
}
// load 8 consecutive f32 from row, convert to bf16x8 fragment
__device__ __forceinline__ bf16x8 ldA(const float* p) {
  float4 u0 = *(const float4*)p;
  float4 u1 = *(const float4*)(p + 4);
  u32x4 w = {pack2(u0.x, u0.y), pack2(u0.z, u0.w), pack2(u1.x, u1.y), pack2(u1.z, u1.w)};
  return __builtin_bit_cast(bf16x8, w);
}

// ---------------- prep: weights -> bf16, send/recv (x handled in GEMMs) ----------------
__global__ __launch_bounds__(256) void k_prep(const float* __restrict__ action,
                                              const float* __restrict__ wmsg, const float* __restrict__ wupd,
                                              short* __restrict__ wmsgb, short* __restrict__ wupdb,
                                              float* __restrict__ send, float* __restrict__ recv) {
  int i = blockIdx.x * 256 + threadIdx.x;
  if (i < FDIM * FDIM) {
    wmsgb[i] = (short)f2b(wmsg[i]);
    wupdb[i] = (short)f2b(wupd[i]);
  }
  if (i < N_NODESC) {
    float a0 = action[i * 3 + 0], a1 = action[i * 3 + 1], a2 = action[i * 3 + 2];
    send[i] = a0 + a2;
    recv[i] = a0 + a1;
  }
}

// ---------------- bucket histogram: per-block LDS 400 bins -> coalesced partials ----------------
__global__ __launch_bounds__(256) void k_bhist(const int* __restrict__ pn, const int* __restrict__ pe,
                                               int* __restrict__ part) {
  __shared__ int h[2 * NB];
  int t = threadIdx.x;
  for (int i = t; i < 2 * NB; i += 256) h[i] = 0;
  __syncthreads();
  int base = blockIdx.x * BH_CHUNK;
  for (int q = t; q < BH_CHUNK / 4; q += 256) {
    int idx = base + q * 4;
    i32x4 e4 = __builtin_nontemporal_load((const i32x4*)(pe + idx));
    i32x4 v4 = __builtin_nontemporal_load((const i32x4*)(pn + idx));
#pragma unroll
    for (int j = 0; j < 4; j++) {
      atomicAdd(&h[e4[j] / EPB], 1);
      atomicAdd(&h[NB + v4[j] / NPB], 1);
    }
  }
  __syncthreads();
  for (int i = t; i < 2 * NB; i += 256) part[blockIdx.x * 2 * NB + i] = h[i];
}

// ---------------- scan helper ----------------
__device__ __forceinline__ int wave_incl_scan(int v, int lane) {
#pragma unroll
  for (int d = 1; d < 64; d <<= 1) {
    int n = __shfl_up(v, d, 64);
    if (lane >= d) v += n;
  }
  return v;
}

// ---------------- reduce partials + scan bucket bases + init cursors ----------------
__global__ __launch_bounds__(256) void k_bscan(const int* __restrict__ part, int* __restrict__ ebase,
                                               int* __restrict__ nbase, int* __restrict__ gcure,
                                               int* __restrict__ gcurn) {
  __shared__ int tot[2 * NB];
  int t = threadIdx.x;
  for (int i = t; i < 2 * NB; i += 256) {
    int s = 0;
    for (int b = 0; b < BH_BLOCKS; b++) s += part[b * 2 * NB + i];
    tot[i] = s;
  }
  __syncthreads();
  if (t < 64) {
    int carry = 0;
    for (int base = 0; base < NB; base += 64) {
      int idx = base + t;
      int v = (idx < NB) ? tot[idx] : 0;
      int inc = wave_incl_scan(v, t);
      if (idx < NB) { ebase[idx] = carry + inc - v; gcure[idx] = carry + inc - v; }
      carry += __shfl(inc, 63, 64);
    }
    if (t == 0) ebase[NB] = N_PAIRSC;
  } else if (t < 128) {
    int lane = t - 64;
    int carry = 0;
    for (int base = 0; base < NB; base += 64) {
      int idx = base + lane;
      int v = (idx < NB) ? tot[NB + idx] : 0;
      int inc = wave_incl_scan(v, lane);
      if (idx < NB) { nbase[idx] = carry + inc - v; gcurn[idx] = carry + inc - v; }
      carry += __shfl(inc, 63, 64);
    }
    if (lane == 0) nbase[NB] = N_PAIRSC;
  }
}

// ---------------- phase A: coarse bucket partition (31-bit packed items) ----------------
__global__ __launch_bounds__(256) void k_part(const int* __restrict__ pn, const int* __restrict__ pe,
                                              int* __restrict__ gcure, int* __restrict__ gcurn,
                                              unsigned* __restrict__ buckE,
                                              unsigned* __restrict__ buckN) {
  __shared__ int ce[NB], cn[NB];
  int t = threadIdx.x;
  for (int i = t; i < NB; i += 256) { ce[i] = 0; cn[i] = 0; }
  __syncthreads();
  long long base = (long long)blockIdx.x * PA_CHUNK;
  for (int q = t; q < PA_CHUNK / 4; q += 256) {
    long long idx = base + (long long)q * 4;
    if (idx >= N_PAIRSC) break;
    i32x4 e4 = __builtin_nontemporal_load((const i32x4*)(pe + idx));
    i32x4 v4 = __builtin_nontemporal_load((const i32x4*)(pn + idx));
#pragma unroll
    for (int j = 0; j < 4; j++) {
      atomicAdd(&ce[e4[j] / EPB], 1);
      atomicAdd(&cn[v4[j] / NPB], 1);
    }
  }
  __syncthreads();
  for (int i = t; i < NB; i += 256) {
    ce[i] = atomicAdd(&gcure[i], ce[i]);
    cn[i] = atomicAdd(&gcurn[i], cn[i]);
  }
  __syncthreads();
  for (int q = t; q < PA_CHUNK / 4; q += 256) {
    long long idx = base + (long long)q * 4;
    if (idx >= N_PAIRSC) break;
    i32x4 e4 = __builtin_nontemporal_load((const i32x4*)(pe + idx));
    i32x4 v4 = __builtin_nontemporal_load((const i32x4*)(pn + idx));
#pragma unroll
    for (int j = 0; j < 4; j++) {
      unsigned ee = (unsigned)e4[j], vv = (unsigned)v4[j];
      int p1 = atomicAdd(&ce[ee / EPB], 1);
      buckE[p1] = (ee << 17) | vv;          // edge key (14b) | node val (17b)
      int p2 = atomicAdd(&cn[vv / NPB], 1);
      buckN[p2] = (vv << 14) | ee;          // node key (17b) | edge val (14b)
    }
  }
}

// ---------------- phase B: fine scatter + per-key counts/offsets from bucket ----------------
__global__ __launch_bounds__(256) void k_fine(const unsigned* __restrict__ buckE,
                                              const unsigned* __restrict__ buckN,
                                              const int* __restrict__ ebase, const int* __restrict__ nbase,
                                              int* __restrict__ ecnt, int* __restrict__ eoff,
                                              int* __restrict__ ncnt, int* __restrict__ noff,
                                              int* __restrict__ sn, int* __restrict__ se) {
  __shared__ int cnt_s[NPB], cur_s[NPB];
  int b = blockIdx.x, t = threadIdx.x;
  const unsigned* buck;
  int *kcnt, *koff, *out;
  int keys, lo, beg, end, shift, mask;
  if (b < NB) {
    buck = buckE; kcnt = ecnt; koff = eoff; out = sn;
    keys = EPB; lo = b * EPB; beg = ebase[b]; end = ebase[b + 1];
    shift = 17; mask = 0x1FFFF;
  } else {
    int bb = b - NB;
    buck = buckN; kcnt = ncnt; koff = noff; out = se;
    keys = NPB; lo = bb * NPB; beg = nbase[bb]; end = nbase[bb + 1];
    shift = 14; mask = 0x3FFF;
  }
  for (int i = t; i < keys; i += 256) cnt_s[i] = 0;
  __syncthreads();
  for (int i = beg + t; i < end; i += 256) {
    int key = (int)(buck[i] >> shift) - lo;
    atomicAdd(&cnt_s[key], 1);
  }
  __syncthreads();
  if (t < 64) {
    int carry = beg;
    for (int base = 0; base < keys; base += 64) {
      int idx = base + t;
      int v = (idx < keys) ? cnt_s[idx] : 0;
      int inc = wave_incl_scan(v, t);
      if (idx < keys) cur_s[idx] = carry + inc - v;
      carry += __shfl(inc, 63, 64);
    }
  }
  __syncthreads();
  for (int i = t; i < keys; i += 256) {
    kcnt[lo + i] = cnt_s[i];
    koff[lo + i] = cur_s[i];
  }
  __syncthreads();
  for (int i = beg + t; i < end; i += 256) {
    unsigned u = buck[i];
    int key = (int)(u >> shift) - lo;
    int val = (int)(u & mask);
    int pos = atomicAdd(&cur_s[key], 1);
    out[pos] = val;
  }
}

// ---------------- GEMM 1: m_ji = gelu(x @ Wmsg^T) * send  -> fp8, 32 rows/wave ----------------
__global__ __launch_bounds__(256) void k_gemm_msg(const float* __restrict__ x, const short* __restrict__ wb,
                                                  const float* __restrict__ send,
                                                  unsigned char* __restrict__ mji8) {
  int gw = (blockIdx.x * 256 + threadIdx.x) >> 6;
  int lane = threadIdx.x & 63;
  if (gw >= N_NODESC / 32) return;
  int rb = gw * 32;
  int lr = lane & 15, lg = lane >> 4;

  bf16x8 A0[4], A1[4];
  const float* xrow0 = x + (size_t)(rb + lr) * FDIM + lg * 8;
  const float* xrow1 = xrow0 + 16 * FDIM;
#pragma unroll
  for (int kk = 0; kk < 4; kk++) {
    A0[kk] = ldA(xrow0 + kk * 32);
    A1[kk] = ldA(xrow1 + kk * 32);
  }

  float sv0[4], sv1[4];
#pragma unroll
  for (int j = 0; j < 4; j++) {
    sv0[j] = send[rb + lg * 4 + j];
    sv1[j] = send[rb + 16 + lg * 4 + j];
  }

#pragma unroll
  for (int c = 0; c < 8; c++) {
    f32x4 acc0 = {0.f, 0.f, 0.f, 0.f}, acc1 = {0.f, 0.f, 0.f, 0.f};
    const short* wrow = wb + (size_t)(16 * c + lr) * FDIM + lg * 8;
#pragma unroll
    for (int kk = 0; kk < 4; kk++) {
      bf16x8 B = *(const bf16x8*)(wrow + kk * 32);
      acc0 = __builtin_amdgcn_mfma_f32_16x16x32_bf16(A0[kk], B, acc0, 0, 0, 0);
      acc1 = __builtin_amdgcn_mfma_f32_16x16x32_bf16(A1[kk], B, acc1, 0, 0, 0);
    }
    int col = 16 * c + lr;
#pragma unroll
    for (int j = 0; j < 4; j++) {
      float m0 = gelu_fast(acc0[j]) * sv0[j];
      float m1 = gelu_fast(acc1[j]) * sv1[j];
      int row0 = rb + lg * 4 + j;
      mji8[(size_t)row0 * FDIM + col] =
          (unsigned char)(__builtin_amdgcn_cvt_pk_fp8_f32(m0, m0, 0, false) & 0xFF);
      mji8[(size_t)(row0 + 16) * FDIM + col] =
          (unsigned char)(__builtin_amdgcn_cvt_pk_fp8_f32(m1, m1, 0, false) & 0xFF);
    }
  }
}

// ---------------- edge reduce: 2 edges/wave, 2 subs per edge, packed f32x2 acc ----------------
__global__ __launch_bounds__(256) void k_edge(const unsigned char* __restrict__ mji8, const int* __restrict__ sn,
                                              const int* __restrict__ eoff, const int* __restrict__ ecnt,
                                              unsigned char* __restrict__ efeat8) {
  int wave = blockIdx.x * 4 + (threadIdx.x >> 6);
  int lane = threadIdx.x & 63;
  int half = lane >> 5;          // which edge of the 2
  int sub2 = (lane >> 4) & 1;    // which pair-interleave within the edge
  int c4 = lane & 15;
  int edge = wave * 2 + half;
  if (edge >= N_EDGESC) return;
  int beg = eoff[edge], cnt = ecnt[edge];
  f32x2 a0 = {0.f, 0.f}, a1 = {0.f, 0.f}, a2 = {0.f, 0.f}, a3 = {0.f, 0.f};
#pragma unroll 4
  for (int p = sub2; p < cnt; p += 2) {
    int node = sn[beg + p];
    uint2 u = ((const uint2*)(mji8 + (size_t)node * FDIM))[c4];
    a0 += __builtin_amdgcn_cvt_pk_f32_fp8(u.x, false);
    a1 += __builtin_amdgcn_cvt_pk_f32_fp8(u.x, true);
    a2 += __builtin_amdgcn_cvt_pk_f32_fp8(u.y, false);
    a3 += __builtin_amdgcn_cvt_pk_f32_fp8(u.y, true);
  }
  a0[0] += __shfl_xor(a0[0], 16, 64); a0[1] += __shfl_xor(a0[1], 16, 64);
  a1[0] += __shfl_xor(a1[0], 16, 64); a1[1] += __shfl_xor(a1[1], 16, 64);
  a2[0] += __shfl_xor(a2[0], 16, 64); a2[1] += __shfl_xor(a2[1], 16, 64);
  a3[0] += __shfl_xor(a3[0], 16, 64); a3[1] += __shfl_xor(a3[1], 16, 64);
  if (sub2 == 0) {
    float inv = 1.0f / fmaxf((float)cnt, 1.0f);
    uint2 o;
    o.x = (unsigned)__builtin_amdgcn_cvt_pk_fp8_f32(a0[0] * inv, a0[1] * inv, 0, false);
    o.x = (unsigned)__builtin_amdgcn_cvt_pk_fp8_f32(a1[0] * inv, a1[1] * inv, (int)o.x, true);
    o.y = (unsigned)__builtin_amdgcn_cvt_pk_fp8_f32(a2[0] * inv, a2[1] * inv, 0, false);
    o.y = (unsigned)__builtin_amdgcn_cvt_pk_fp8_f32(a3[0] * inv, a3[1] * inv, (int)o.y, true);
    ((uint2*)(efeat8 + (size_t)edge * FDIM))[c4] = o;
  }
}

// ---------------- node reduce: one node per 16-lane sub (4 nodes/wave) ----------------
__global__ __launch_bounds__(256) void k_node(const unsigned char* __restrict__ efeat8, const int* __restrict__ se,
                                              const int* __restrict__ noff, const int* __restrict__ ncnt,
                                              const float* __restrict__ recv, short* __restrict__ mi) {
  int wave = blockIdx.x * 4 + (threadIdx.x >> 6);
  int lane = threadIdx.x & 63;
  int sub = lane >> 4, c4 = lane & 15;
  int node = wave * 4 + sub;   // 25000 waves x 4 = 100000 exactly
  int beg = noff[node], cnt = ncnt[node];
  f32x2 a0 = {0.f, 0.f}, a1 = {0.f, 0.f}, a2 = {0.f, 0.f}, a3 = {0.f, 0.f};
#pragma unroll 4
  for (int p = 0; p < cnt; p++) {
    int e = se[beg + p];
    uint2 u = ((const uint2*)(efeat8 + (size_t)e * FDIM))[c4];
    a0 += __builtin_amdgcn_cvt_pk_f32_fp8(u.x, false);
    a1 += __builtin_amdgcn_cvt_pk_f32_fp8(u.x, true);
    a2 += __builtin_amdgcn_cvt_pk_f32_fp8(u.y, false);
    a3 += __builtin_amdgcn_cvt_pk_f32_fp8(u.y, true);
  }
  float s = recv[node] / fmaxf((float)cnt, 1.0f);
  u32x4 o;
  o[0] = pack2(a0[0] * s, a0[1] * s);
  o[1] = pack2(a1[0] * s, a1[1] * s);
  o[2] = pack2(a2[0] * s, a2[1] * s);
  o[3] = pack2(a3[0] * s, a3[1] * s);
  ((u32x4*)(mi + (size_t)node * FDIM))[c4] = o;
}

// ---------------- GEMM 2: out = gelu(x @ Wupd^T + b + m_i) -> f32, 32 rows/wave ----------------
__global__ __launch_bounds__(256) void k_gemm_upd(const float* __restrict__ x, const short* __restrict__ wb,
                                                  const float* __restrict__ bias, const short* __restrict__ mi,
                                                  float* __restrict__ out) {
  int gw = (blockIdx.x * 256 + threadIdx.x) >> 6;
  int lane = threadIdx.x & 63;
  if (gw >= N_NODESC / 32) return;
  int rb = gw * 32;
  int lr = lane & 15, lg = lane >> 4;

  bf16x8 A0[4], A1[4];
  const float* xrow0 = x + (size_t)(rb + lr) * FDIM + lg * 8;
  const float* xrow1 = xrow0 + 16 * FDIM;
#pragma unroll
  for (int kk = 0; kk < 4; kk++) {
    A0[kk] = ldA(xrow0 + kk * 32);
    A1[kk] = ldA(xrow1 + kk * 32);
  }

#pragma unroll
  for (int c = 0; c < 8; c++) {
    f32x4 acc0 = {0.f, 0.f, 0.f, 0.f}, acc1 = {0.f, 0.f, 0.f, 0.f};
    const short* wrow = wb + (size_t)(16 * c + lr) * FDIM + lg * 8;
#pragma unroll
    for (int kk = 0; kk < 4; kk++) {
      bf16x8 B = *(const bf16x8*)(wrow + kk * 32);
      acc0 = __builtin_amdgcn_mfma_f32_16x16x32_bf16(A0[kk], B, acc0, 0, 0, 0);
      acc1 = __builtin_amdgcn_mfma_f32_16x16x32_bf16(A1[kk], B, acc1, 0, 0, 0);
    }
    int col = 16 * c + lr;
    float bc = bias[col];
#pragma unroll
    for (int j = 0; j < 4; j++) {
      int row0 = rb + lg * 4 + j;
      float z0 = acc0[j] + bc + b2f(((const unsigned short*)mi)[(size_t)row0 * FDIM + col]);
      float z1 = acc1[j] + bc + b2f(((const unsigned short*)mi)[(size_t)(row0 + 16) * FDIM + col]);
      __builtin_nontemporal_store(gelu_fast(z0), &out[(size_t)row0 * FDIM + col]);
      __builtin_nontemporal_store(gelu_fast(z1), &out[(size_t)(row0 + 16) * FDIM + col]);
    }
  }
}

extern "C" void kernel_launch(void* const* d_in, const int* in_sizes, int n_in,
                              void* d_out, int out_size, void* d_ws, size_t ws_size,
                              hipStream_t stream) {
  const float* x = (const float*)d_in[0];
  const float* action = (const float*)d_in[1];
  const float* wmsg = (const float*)d_in[2];
  const float* wupd = (const float*)d_in[3];
  const float* bupd = (const float*)d_in[4];
  const int* pn = (const int*)d_in[5];
  const int* pe = (const int*)d_in[6];
  float* out = (float*)d_out;

  char* p = (char*)d_ws;
  auto alloc = [&](size_t bytes) -> char* {
    char* r = p;
    p += (bytes + 255) & ~(size_t)255;
    return r;
  };
  unsigned char* mji8 = (unsigned char*)alloc((size_t)N_NODESC * FDIM);
  short* mi = (short*)alloc((size_t)N_NODESC * FDIM * 2);   // also hosts buckE+buckN (consumed before k_node writes mi)
  unsigned char* efeat8 = (unsigned char*)alloc((size_t)N_EDGESC * FDIM);
  int* sn = (int*)alloc((size_t)N_PAIRSC * 4);
  int* se = (int*)alloc((size_t)N_PAIRSC * 4);
  short* wmsgb = (short*)alloc(FDIM * FDIM * 2);
  short* wupdb = (short*)alloc(FDIM * FDIM * 2);
  float* send = (float*)alloc(N_NODESC * 4);
  float* recv = (float*)alloc(N_NODESC * 4);
  int* ecnt = (int*)alloc(N_EDGESC * 4);
  int* eoff = (int*)alloc(N_EDGESC * 4);
  int* ncnt = (int*)alloc(N_NODESC * 4);
  int* noff = (int*)alloc(N_NODESC * 4);
  int* part = (int*)alloc((size_t)BH_BLOCKS * 2 * NB * 4);
  int* ebase = (int*)alloc((NB + 1) * 4);
  int* nbase = (int*)alloc((NB + 1) * 4);
  int* gcure = (int*)alloc(NB * 4);
  int* gcurn = (int*)alloc(NB * 4);

  unsigned* buckE = (unsigned*)mi;                      // 6.4 MB
  unsigned* buckN = buckE + (size_t)N_PAIRSC;           // 6.4 MB (fits mi's 25.6 MB region)

  k_prep<<<391, 256, 0, stream>>>(action, wmsg, wupd, wmsgb, wupdb, send, recv);
  k_bhist<<<BH_BLOCKS, 256, 0, stream>>>(pn, pe, part);
  k_bscan<<<1, 256, 0, stream>>>(part, ebase, nbase, gcure, gcurn);
  k_part<<<PA_NCH, 256, 0, stream>>>(pn, pe, gcure, gcurn, buckE, buckN);
  k_fine<<<2 * NB, 256, 0, stream>>>(buckE, buckN, ebase, nbase, ecnt, eoff, ncnt, noff, sn, se);
  k_gemm_msg<<<782, 256, 0, stream>>>(x, wmsgb, send, mji8);
  k_edge<<<1250, 256, 0, stream>>>(mji8, sn, eoff, ecnt, efeat8);
  k_node<<<6250, 256, 0, stream>>>(efeat8, se, noff, ncnt, recv, mi);
  k_gemm_upd<<<782, 256, 0, stream>>>(x, wupdb, bupd, mi, out);
}

// Round 13
// 184.920 us; speedup vs baseline: 1.6764x; 1.1591x over previous
//
#include <hip/hip_runtime.h>

#define N_NODESC 100000
#define N_EDGESC 10000
#define N_PAIRSC 1600000
#define FDIM 128

#define NB 200       // buckets per path
#define EPB 50       // edges per bucket  (200*50 = 10000)
#define NPB 500      // nodes per bucket  (200*500 = 100000)
#define ECAP2 8704   // fixed bucket stride; mean 8000, sigma 89 -> 7.9 sigma slack
#define PA_CHUNK 8192
#define PA_NCH ((N_PAIRSC + PA_CHUNK - 1) / PA_CHUNK)  // 196

typedef short bf16x8 __attribute__((ext_vector_type(8)));
typedef float f32x4 __attribute__((ext_vector_type(4)));
typedef float f32x2 __attribute__((ext_vector_type(2)));
typedef int i32x4 __attribute__((ext_vector_type(4)));
typedef unsigned u32x4 __attribute__((ext_vector_type(4)));

__device__ __forceinline__ unsigned short f2b(float f) {
  unsigned u = __float_as_uint(f);
  u += 0x7fffu + ((u >> 16) & 1u);
  return (unsigned short)(u >> 16);
}
__device__ __forceinline__ float b2f(unsigned short b) {
  return __uint_as_float(((unsigned)b) << 16);
}
__device__ __forceinline__ unsigned pack2(float a, float b) {
  return (unsigned)f2b(a) | ((unsigned)f2b(b) << 16);
}
// tanh-form gelu: z*e/(e+1), e=exp(1.59576912*z*(1+0.044715 z^2)). |diff| <= ~1e-3.
__device__ __forceinline__ float gelu_fast(float z) {
  float z2 = z * z;
  float w = fmaf(0.044715f, z2, 1.0f);
  float e = __expf(1.5957691216f * z * w);
  return z * e * __builtin_amdgcn_rcpf(e + 1.0f);
}
// load 8 consecutive f32 from row, convert to bf16x8 fragment
__device__ __forceinline__ bf16x8 ldA(const float* p) {
  float4 u0 = *(const float4*)p;
  float4 u1 = *(const float4*)(p + 4);
  u32x4 w = {pack2(u0.x, u0.y), pack2(u0.z, u0.w), pack2(u1.x, u1.y), pack2(u1.z, u1.w)};
  return __builtin_bit_cast(bf16x8, w);
}

// ---------------- prep: weights -> bf16, send/recv, bucket cursor init ----------------
__global__ __launch_bounds__(256) void k_prep(const float* __restrict__ action,
                                              const float* __restrict__ wmsg, const float* __restrict__ wupd,
                                              short* __restrict__ wmsgb, short* __restrict__ wupdb,
                                              float* __restrict__ send, float* __restrict__ recv,
                                              int* __restrict__ gcure, int* __restrict__ gcurn) {
  int i = blockIdx.x * 256 + threadIdx.x;
  if (i < FDIM * FDIM) {
    wmsgb[i] = (short)f2b(wmsg[i]);
    wupdb[i] = (short)f2b(wupd[i]);
  }
  if (i < N_NODESC) {
    float a0 = action[i * 3 + 0], a1 = action[i * 3 + 1], a2 = action[i * 3 + 2];
    send[i] = a0 + a2;
    recv[i] = a0 + a1;
  }
  if (i < NB) {
    gcure[i] = i * ECAP2;
    gcurn[i] = i * ECAP2;
  }
}

// ---------------- scan helper ----------------
__device__ __forceinline__ int wave_incl_scan(int v, int lane) {
#pragma unroll
  for (int d = 1; d < 64; d <<= 1) {
    int n = __shfl_up(v, d, 64);
    if (lane >= d) v += n;
  }
  return v;
}

// ---------------- phase A: coarse bucket partition into fixed-stride slack buckets ----------------
__global__ __launch_bounds__(256) void k_part(const int* __restrict__ pn, const int* __restrict__ pe,
                                              int* __restrict__ gcure, int* __restrict__ gcurn,
                                              unsigned* __restrict__ buckE,
                                              unsigned* __restrict__ buckN) {
  __shared__ int ce[NB], cn[NB];
  int t = threadIdx.x;
  for (int i = t; i < NB; i += 256) { ce[i] = 0; cn[i] = 0; }
  __syncthreads();
  long long base = (long long)blockIdx.x * PA_CHUNK;
  for (int q = t; q < PA_CHUNK / 4; q += 256) {
    long long idx = base + (long long)q * 4;
    if (idx >= N_PAIRSC) break;
    i32x4 e4 = __builtin_nontemporal_load((const i32x4*)(pe + idx));
    i32x4 v4 = __builtin_nontemporal_load((const i32x4*)(pn + idx));
#pragma unroll
    for (int j = 0; j < 4; j++) {
      atomicAdd(&ce[e4[j] / EPB], 1);
      atomicAdd(&cn[v4[j] / NPB], 1);
    }
  }
  __syncthreads();
  for (int i = t; i < NB; i += 256) {
    ce[i] = atomicAdd(&gcure[i], ce[i]);
    cn[i] = atomicAdd(&gcurn[i], cn[i]);
  }
  __syncthreads();
  for (int q = t; q < PA_CHUNK / 4; q += 256) {
    long long idx = base + (long long)q * 4;
    if (idx >= N_PAIRSC) break;
    i32x4 e4 = __builtin_nontemporal_load((const i32x4*)(pe + idx));
    i32x4 v4 = __builtin_nontemporal_load((const i32x4*)(pn + idx));
#pragma unroll
    for (int j = 0; j < 4; j++) {
      unsigned ee = (unsigned)e4[j], vv = (unsigned)v4[j];
      int p1 = atomicAdd(&ce[ee / EPB], 1);
      buckE[p1] = (ee << 17) | vv;          // edge key (14b) | node val (17b)
      int p2 = atomicAdd(&cn[vv / NPB], 1);
      buckN[p2] = (vv << 14) | ee;          // node key (17b) | edge val (14b)
    }
  }
}

// ---------------- phase B: fine scatter + per-key counts/offsets from bucket ----------------
__global__ __launch_bounds__(256) void k_fine(const unsigned* __restrict__ buckE,
                                              const unsigned* __restrict__ buckN,
                                              const int* __restrict__ gcure, const int* __restrict__ gcurn,
                                              int* __restrict__ ecnt, int* __restrict__ eoff,
                                              int* __restrict__ ncnt, int* __restrict__ noff,
                                              int* __restrict__ sn, int* __restrict__ se) {
  __shared__ int cnt_s[NPB], cur_s[NPB];
  int b = blockIdx.x, t = threadIdx.x;
  const unsigned* buck;
  int *kcnt, *koff, *out;
  int keys, lo, beg, end, shift, mask;
  if (b < NB) {
    buck = buckE; kcnt = ecnt; koff = eoff; out = sn;
    keys = EPB; lo = b * EPB; beg = b * ECAP2; end = gcure[b];
    shift = 17; mask = 0x1FFFF;
  } else {
    int bb = b - NB;
    buck = buckN; kcnt = ncnt; koff = noff; out = se;
    keys = NPB; lo = bb * NPB; beg = bb * ECAP2; end = gcurn[bb];
    shift = 14; mask = 0x3FFF;
  }
  for (int i = t; i < keys; i += 256) cnt_s[i] = 0;
  __syncthreads();
  for (int i = beg + t; i < end; i += 256) {
    int key = (int)(buck[i] >> shift) - lo;
    atomicAdd(&cnt_s[key], 1);
  }
  __syncthreads();
  if (t < 64) {
    int carry = beg;
    for (int base = 0; base < keys; base += 64) {
      int idx = base + t;
      int v = (idx < keys) ? cnt_s[idx] : 0;
      int inc = wave_incl_scan(v, t);
      if (idx < keys) cur_s[idx] = carry + inc - v;
      carry += __shfl(inc, 63, 64);
    }
  }
  __syncthreads();
  for (int i = t; i < keys; i += 256) {
    kcnt[lo + i] = cnt_s[i];
    koff[lo + i] = cur_s[i];
  }
  __syncthreads();
  for (int i = beg + t; i < end; i += 256) {
    unsigned u = buck[i];
    int key = (int)(u >> shift) - lo;
    int val = (int)(u & mask);
    int pos = atomicAdd(&cur_s[key], 1);
    out[pos] = val;
  }
}

// ---------------- GEMM 1: m_ji = gelu(x @ Wmsg^T) * send  -> fp8, 32 rows/wave ----------------
__global__ __launch_bounds__(256) void k_gemm_msg(const float* __restrict__ x, const short* __restrict__ wb,
                                                  const float* __restrict__ send,
                                                  unsigned char* __restrict__ mji8) {
  int gw = (blockIdx.x * 256 + threadIdx.x) >> 6;
  int lane = threadIdx.x & 63;
  if (gw >= N_NODESC / 32) return;
  int rb = gw * 32;
  int lr = lane & 15, lg = lane >> 4;

  bf16x8 A0[4], A1[4];
  const float* xrow0 = x + (size_t)(rb + lr) * FDIM + lg * 8;
  const float* xrow1 = xrow0 + 16 * FDIM;
#pragma unroll
  for (int kk = 0; kk < 4; kk++) {
    A0[kk] = ldA(xrow0 + kk * 32);
    A1[kk] = ldA(xrow1 + kk * 32);
  }

  float sv0[4], sv1[4];
#pragma unroll
  for (int j = 0; j < 4; j++) {
    sv0[j] = send[rb + lg * 4 + j];
    sv1[j] = send[rb + 16 + lg * 4 + j];
  }

#pragma unroll
  for (int c = 0; c < 8; c++) {
    f32x4 acc0 = {0.f, 0.f, 0.f, 0.f}, acc1 = {0.f, 0.f, 0.f, 0.f};
    const short* wrow = wb + (size_t)(16 * c + lr) * FDIM + lg * 8;
#pragma unroll
    for (int kk = 0; kk < 4; kk++) {
      bf16x8 B = *(const bf16x8*)(wrow + kk * 32);
      acc0 = __builtin_amdgcn_mfma_f32_16x16x32_bf16(A0[kk], B, acc0, 0, 0, 0);
      acc1 = __builtin_amdgcn_mfma_f32_16x16x32_bf16(A1[kk], B, acc1, 0, 0, 0);
    }
    int col = 16 * c + lr;
#pragma unroll
    for (int j = 0; j < 4; j++) {
      float m0 = gelu_fast(acc0[j]) * sv0[j];
      float m1 = gelu_fast(acc1[j]) * sv1[j];
      int row0 = rb + lg * 4 + j;
      mji8[(size_t)row0 * FDIM + col] =
          (unsigned char)(__builtin_amdgcn_cvt_pk_fp8_f32(m0, m0, 0, false) & 0xFF);
      mji8[(size_t)(row0 + 16) * FDIM + col] =
          (unsigned char)(__builtin_amdgcn_cvt_pk_fp8_f32(m1, m1, 0, false) & 0xFF);
    }
  }
}

// ---------------- edge reduce: 2 edges/wave, 2 subs per edge, packed f32x2 acc ----------------
__global__ __launch_bounds__(256) void k_edge(const unsigned char* __restrict__ mji8, const int* __restrict__ sn,
                                              const int* __restrict__ eoff, const int* __restrict__ ecnt,
                                              unsigned char* __restrict__ efeat8) {
  int wave = blockIdx.x * 4 + (threadIdx.x >> 6);
  int lane = threadIdx.x & 63;
  int half = lane >> 5;          // which edge of the 2
  int sub2 = (lane >> 4) & 1;    // which pair-interleave within the edge
  int c4 = lane & 15;
  int edge = wave * 2 + half;
  if (edge >= N_EDGESC) return;
  int beg = eoff[edge], cnt = ecnt[edge];
  f32x2 a0 = {0.f, 0.f}, a1 = {0.f, 0.f}, a2 = {0.f, 0.f}, a3 = {0.f, 0.f};
#pragma unroll 4
  for (int p = sub2; p < cnt; p += 2) {
    int node = sn[beg + p];
    uint2 u = ((const uint2*)(mji8 + (size_t)node * FDIM))[c4];
    a0 += __builtin_amdgcn_cvt_pk_f32_fp8(u.x, false);
    a1 += __builtin_amdgcn_cvt_pk_f32_fp8(u.x, true);
    a2 += __builtin_amdgcn_cvt_pk_f32_fp8(u.y, false);
    a3 += __builtin_amdgcn_cvt_pk_f32_fp8(u.y, true);
  }
  a0[0] += __shfl_xor(a0[0], 16, 64); a0[1] += __shfl_xor(a0[1], 16, 64);
  a1[0] += __shfl_xor(a1[0], 16, 64); a1[1] += __shfl_xor(a1[1], 16, 64);
  a2[0] += __shfl_xor(a2[0], 16, 64); a2[1] += __shfl_xor(a2[1], 16, 64);
  a3[0] += __shfl_xor(a3[0], 16, 64); a3[1] += __shfl_xor(a3[1], 16, 64);
  if (sub2 == 0) {
    float inv = 1.0f / fmaxf((float)cnt, 1.0f);
    uint2 o;
    o.x = (unsigned)__builtin_amdgcn_cvt_pk_fp8_f32(a0[0] * inv, a0[1] * inv, 0, false);
    o.x = (unsigned)__builtin_amdgcn_cvt_pk_fp8_f32(a1[0] * inv, a1[1] * inv, (int)o.x, true);
    o.y = (unsigned)__builtin_amdgcn_cvt_pk_fp8_f32(a2[0] * inv, a2[1] * inv, 0, false);
    o.y = (unsigned)__builtin_amdgcn_cvt_pk_fp8_f32(a3[0] * inv, a3[1] * inv, (int)o.y, true);
    ((uint2*)(efeat8 + (size_t)edge * FDIM))[c4] = o;
  }
}

// ---------------- node reduce: one node per 16-lane sub (4 nodes/wave) ----------------
__global__ __launch_bounds__(256) void k_node(const unsigned char* __restrict__ efeat8, const int* __restrict__ se,
                                              const int* __restrict__ noff, const int* __restrict__ ncnt,
                                              const float* __restrict__ recv, short* __restrict__ mi) {
  int wave = blockIdx.x * 4 + (threadIdx.x >> 6);
  int lane = threadIdx.x & 63;
  int sub = lane >> 4, c4 = lane & 15;
  int node = wave * 4 + sub;   // 25000 waves x 4 = 100000 exactly
  int beg = noff[node], cnt = ncnt[node];
  f32x2 a0 = {0.f, 0.f}, a1 = {0.f, 0.f}, a2 = {0.f, 0.f}, a3 = {0.f, 0.f};
#pragma unroll 4
  for (int p = 0; p < cnt; p++) {
    int e = se[beg + p];
    uint2 u = ((const uint2*)(efeat8 + (size_t)e * FDIM))[c4];
    a0 += __builtin_amdgcn_cvt_pk_f32_fp8(u.x, false);
    a1 += __builtin_amdgcn_cvt_pk_f32_fp8(u.x, true);
    a2 += __builtin_amdgcn_cvt_pk_f32_fp8(u.y, false);
    a3 += __builtin_amdgcn_cvt_pk_f32_fp8(u.y, true);
  }
  float s = recv[node] / fmaxf((float)cnt, 1.0f);
  u32x4 o;
  o[0] = pack2(a0[0] * s, a0[1] * s);
  o[1] = pack2(a1[0] * s, a1[1] * s);
  o[2] = pack2(a2[0] * s, a2[1] * s);
  o[3] = pack2(a3[0] * s, a3[1] * s);
  ((u32x4*)(mi + (size_t)node * FDIM))[c4] = o;
}

// ---------------- GEMM 2: out = gelu(x @ Wupd^T + b + m_i) -> f32, 32 rows/wave ----------------
__global__ __launch_bounds__(256) void k_gemm_upd(const float* __restrict__ x, const short* __restrict__ wb,
                                                  const float* __restrict__ bias, const short* __restrict__ mi,
                                                  float* __restrict__ out) {
  int gw = (blockIdx.x * 256 + threadIdx.x) >> 6;
  int lane = threadIdx.x & 63;
  if (gw >= N_NODESC / 32) return;
  int rb = gw * 32;
  int lr = lane & 15, lg = lane >> 4;

  bf16x8 A0[4], A1[4];
  const float* xrow0 = x + (size_t)(rb + lr) * FDIM + lg * 8;
  const float* xrow1 = xrow0 + 16 * FDIM;
#pragma unroll
  for (int kk = 0; kk < 4; kk++) {
    A0[kk] = ldA(xrow0 + kk * 32);
    A1[kk] = ldA(xrow1 + kk * 32);
  }

#pragma unroll
  for (int c = 0; c < 8; c++) {
    f32x4 acc0 = {0.f, 0.f, 0.f, 0.f}, acc1 = {0.f, 0.f, 0.f, 0.f};
    const short* wrow = wb + (size_t)(16 * c + lr) * FDIM + lg * 8;
#pragma unroll
    for (int kk = 0; kk < 4; kk++) {
      bf16x8 B = *(const bf16x8*)(wrow + kk * 32);
      acc0 = __builtin_amdgcn_mfma_f32_16x16x32_bf16(A0[kk], B, acc0, 0, 0, 0);
      acc1 = __builtin_amdgcn_mfma_f32_16x16x32_bf16(A1[kk], B, acc1, 0, 0, 0);
    }
    int col = 16 * c + lr;
    float bc = bias[col];
#pragma unroll
    for (int j = 0; j < 4; j++) {
      int row0 = rb + lg * 4 + j;
      float z0 = acc0[j] + bc + b2f(((const unsigned short*)mi)[(size_t)row0 * FDIM + col]);
      float z1 = acc1[j] + bc + b2f(((const unsigned short*)mi)[(size_t)(row0 + 16) * FDIM + col]);
      __builtin_nontemporal_store(gelu_fast(z0), &out[(size_t)row0 * FDIM + col]);
      __builtin_nontemporal_store(gelu_fast(z1), &out[(size_t)(row0 + 16) * FDIM + col]);
    }
  }
}

extern "C" void kernel_launch(void* const* d_in, const int* in_sizes, int n_in,
                              void* d_out, int out_size, void* d_ws, size_t ws_size,
                              hipStream_t stream) {
  const float* x = (const float*)d_in[0];
  const float* action = (const float*)d_in[1];
  const float* wmsg = (const float*)d_in[2];
  const float* wupd = (const float*)d_in[3];
  const float* bupd = (const float*)d_in[4];
  const int* pn = (const int*)d_in[5];
  const int* pe = (const int*)d_in[6];
  float* out = (float*)d_out;

  char* p = (char*)d_ws;
  auto alloc = [&](size_t bytes) -> char* {
    char* r = p;
    p += (bytes + 255) & ~(size_t)255;
    return r;
  };
  unsigned char* mji8 = (unsigned char*)alloc((size_t)N_NODESC * FDIM);
  short* mi = (short*)alloc((size_t)N_NODESC * FDIM * 2);   // also hosts buckE+buckN (consumed before k_node writes mi)
  unsigned char* efeat8 = (unsigned char*)alloc((size_t)N_EDGESC * FDIM);
  int* sn = (int*)alloc((size_t)NB * ECAP2 * 4);
  int* se = (int*)alloc((size_t)NB * ECAP2 * 4);
  short* wmsgb = (short*)alloc(FDIM * FDIM * 2);
  short* wupdb = (short*)alloc(FDIM * FDIM * 2);
  float* send = (float*)alloc(N_NODESC * 4);
  float* recv = (float*)alloc(N_NODESC * 4);
  int* ecnt = (int*)alloc(N_EDGESC * 4);
  int* eoff = (int*)alloc(N_EDGESC * 4);
  int* ncnt = (int*)alloc(N_NODESC * 4);
  int* noff = (int*)alloc(N_NODESC * 4);
  int* gcure = (int*)alloc(NB * 4);
  int* gcurn = (int*)alloc(NB * 4);

  unsigned* buckE = (unsigned*)mi;                               // 6.96 MB
  unsigned* buckN = buckE + (size_t)NB * ECAP2;                  // 6.96 MB (fits mi's 25.6 MB region)

  k_prep<<<391, 256, 0, stream>>>(action, wmsg, wupd, wmsgb, wupdb, send, recv, gcure, gcurn);
  k_part<<<PA_NCH, 256, 0, stream>>>(pn, pe, gcure, gcurn, buckE, buckN);
  k_fine<<<2 * NB, 256, 0, stream>>>(buckE, buckN, gcure, gcurn, ecnt, eoff, ncnt, noff, sn, se);
  k_gemm_msg<<<782, 256, 0, stream>>>(x, wmsgb, send, mji8);
  k_edge<<<1250, 256, 0, stream>>>(mji8, sn, eoff, ecnt, efeat8);
  k_node<<<6250, 256, 0, stream>>>(efeat8, se, noff, ncnt, recv, mi);
  k_gemm_upd<<<782, 256, 0, stream>>>(x, wupdb, bupd, mi, out);
}

// Round 14
// 175.502 us; speedup vs baseline: 1.7664x; 1.0537x over previous
//
#include <hip/hip_runtime.h>

#define N_NODESC 100000
#define N_EDGESC 10000
#define N_PAIRSC 1600000
#define FDIM 128

#define NB 200       // buckets per path
#define EPB 50       // edges per bucket  (200*50 = 10000)
#define NPB 500      // nodes per bucket  (200*500 = 100000)
#define ECAP2 8704   // fixed bucket stride; mean 8000, sigma 89 -> 7.9 sigma slack
#define PA_CHUNK 8192
#define PA_NCH ((N_PAIRSC + PA_CHUNK - 1) / PA_CHUNK)  // 196
#define MSG_BLKS 782

typedef short bf16x8 __attribute__((ext_vector_type(8)));
typedef float f32x4 __attribute__((ext_vector_type(4)));
typedef float f32x2 __attribute__((ext_vector_type(2)));
typedef int i32x4 __attribute__((ext_vector_type(4)));
typedef unsigned u32x4 __attribute__((ext_vector_type(4)));

__device__ __forceinline__ unsigned short f2b(float f) {
  unsigned u = __float_as_uint(f);
  u += 0x7fffu + ((u >> 16) & 1u);
  return (unsigned short)(u >> 16);
}
__device__ __forceinline__ float b2f(unsigned short b) {
  return __uint_as_float(((unsigned)b) << 16);
}
__device__ __forceinline__ unsigned pack2(float a, float b) {
  return (unsigned)f2b(a) | ((unsigned)f2b(b) << 16);
}
// tanh-form gelu: z*e/(e+1), e=exp(1.59576912*z*(1+0.044715 z^2)). |diff| <= ~1e-3.
__device__ __forceinline__ float gelu_fast(float z) {
  float z2 = z * z;
  float w = fmaf(0.044715f, z2, 1.0f);
  float e = __expf(1.5957691216f * z * w);
  return z * e * __builtin_amdgcn_rcpf(e + 1.0f);
}
// load 8 consecutive f32 from row, convert to bf16x8 fragment
__device__ __forceinline__ bf16x8 ldA(const float* p) {
  float4 u0 = *(const float4*)p;
  float4 u1 = *(const float4*)(p + 4);
  u32x4 w = {pack2(u0.x, u0.y), pack2(u0.z, u0.w), pack2(u1.x, u1.y), pack2(u1.z, u1.w)};
  return __builtin_bit_cast(bf16x8, w);
}

// ---------------- prep: weights -> bf16, send/recv, bucket cursor init ----------------
__global__ __launch_bounds__(256) void k_prep(const float* __restrict__ action,
                                              const float* __restrict__ wmsg, const float* __restrict__ wupd,
                                              short* __restrict__ wmsgb, short* __restrict__ wupdb,
                                              float* __restrict__ send, float* __restrict__ recv,
                                              int* __restrict__ gcure, int* __restrict__ gcurn) {
  int i = blockIdx.x * 256 + threadIdx.x;
  if (i < FDIM * FDIM) {
    wmsgb[i] = (short)f2b(wmsg[i]);
    wupdb[i] = (short)f2b(wupd[i]);
  }
  if (i < N_NODESC) {
    float a0 = action[i * 3 + 0], a1 = action[i * 3 + 1], a2 = action[i * 3 + 2];
    send[i] = a0 + a2;
    recv[i] = a0 + a1;
  }
  if (i < NB) {
    gcure[i] = i * ECAP2;
    gcurn[i] = i * ECAP2;
  }
}

// ---------------- scan helper ----------------
__device__ __forceinline__ int wave_incl_scan(int v, int lane) {
#pragma unroll
  for (int d = 1; d < 64; d <<= 1) {
    int n = __shfl_up(v, d, 64);
    if (lane >= d) v += n;
  }
  return v;
}

// ---------------- fused: k_part (blocks 0..195)  ||  k_gemm_msg (blocks 196..977) ----------------
__global__ __launch_bounds__(256) void k_part_msg(const int* __restrict__ pn, const int* __restrict__ pe,
                                                  int* __restrict__ gcure, int* __restrict__ gcurn,
                                                  unsigned* __restrict__ buckE, unsigned* __restrict__ buckN,
                                                  const float* __restrict__ x, const short* __restrict__ wb,
                                                  const float* __restrict__ send,
                                                  unsigned char* __restrict__ mji8) {
  __shared__ int ce[NB], cn[NB];
  int t = threadIdx.x;
  if (blockIdx.x < PA_NCH) {
    // ---- partition path ----
    for (int i = t; i < NB; i += 256) { ce[i] = 0; cn[i] = 0; }
    __syncthreads();
    long long base = (long long)blockIdx.x * PA_CHUNK;
    for (int q = t; q < PA_CHUNK / 4; q += 256) {
      long long idx = base + (long long)q * 4;
      if (idx >= N_PAIRSC) break;
      i32x4 e4 = __builtin_nontemporal_load((const i32x4*)(pe + idx));
      i32x4 v4 = __builtin_nontemporal_load((const i32x4*)(pn + idx));
#pragma unroll
      for (int j = 0; j < 4; j++) {
        atomicAdd(&ce[e4[j] / EPB], 1);
        atomicAdd(&cn[v4[j] / NPB], 1);
      }
    }
    __syncthreads();
    for (int i = t; i < NB; i += 256) {
      ce[i] = atomicAdd(&gcure[i], ce[i]);
      cn[i] = atomicAdd(&gcurn[i], cn[i]);
    }
    __syncthreads();
    for (int q = t; q < PA_CHUNK / 4; q += 256) {
      long long idx = base + (long long)q * 4;
      if (idx >= N_PAIRSC) break;
      i32x4 e4 = __builtin_nontemporal_load((const i32x4*)(pe + idx));
      i32x4 v4 = __builtin_nontemporal_load((const i32x4*)(pn + idx));
#pragma unroll
      for (int j = 0; j < 4; j++) {
        unsigned ee = (unsigned)e4[j], vv = (unsigned)v4[j];
        int p1 = atomicAdd(&ce[ee / EPB], 1);
        buckE[p1] = (ee << 17) | vv;          // edge key (14b) | node val (17b)
        int p2 = atomicAdd(&cn[vv / NPB], 1);
        buckN[p2] = (vv << 14) | ee;          // node key (17b) | edge val (14b)
      }
    }
  } else {
    // ---- gemm_msg path ----
    int gw = ((int)(blockIdx.x - PA_NCH) * 256 + t) >> 6;
    int lane = t & 63;
    if (gw >= N_NODESC / 32) return;
    int rb = gw * 32;
    int lr = lane & 15, lg = lane >> 4;

    bf16x8 A0[4], A1[4];
    const float* xrow0 = x + (size_t)(rb + lr) * FDIM + lg * 8;
    const float* xrow1 = xrow0 + 16 * FDIM;
#pragma unroll
    for (int kk = 0; kk < 4; kk++) {
      A0[kk] = ldA(xrow0 + kk * 32);
      A1[kk] = ldA(xrow1 + kk * 32);
    }
    float sv0[4], sv1[4];
#pragma unroll
    for (int j = 0; j < 4; j++) {
      sv0[j] = send[rb + lg * 4 + j];
      sv1[j] = send[rb + 16 + lg * 4 + j];
    }
#pragma unroll
    for (int c = 0; c < 8; c++) {
      f32x4 acc0 = {0.f, 0.f, 0.f, 0.f}, acc1 = {0.f, 0.f, 0.f, 0.f};
      const short* wrow = wb + (size_t)(16 * c + lr) * FDIM + lg * 8;
#pragma unroll
      for (int kk = 0; kk < 4; kk++) {
        bf16x8 B = *(const bf16x8*)(wrow + kk * 32);
        acc0 = __builtin_amdgcn_mfma_f32_16x16x32_bf16(A0[kk], B, acc0, 0, 0, 0);
        acc1 = __builtin_amdgcn_mfma_f32_16x16x32_bf16(A1[kk], B, acc1, 0, 0, 0);
      }
      int col = 16 * c + lr;
#pragma unroll
      for (int j = 0; j < 4; j++) {
        float m0 = gelu_fast(acc0[j]) * sv0[j];
        float m1 = gelu_fast(acc1[j]) * sv1[j];
        int row0 = rb + lg * 4 + j;
        mji8[(size_t)row0 * FDIM + col] =
            (unsigned char)(__builtin_amdgcn_cvt_pk_fp8_f32(m0, m0, 0, false) & 0xFF);
        mji8[(size_t)(row0 + 16) * FDIM + col] =
            (unsigned char)(__builtin_amdgcn_cvt_pk_fp8_f32(m1, m1, 0, false) & 0xFF);
      }
    }
  }
}

// ---------------- fine_E: per-edge counts/offsets + sorted sn ----------------
__global__ __launch_bounds__(256) void k_fine_e(const unsigned* __restrict__ buckE,
                                                const int* __restrict__ gcure,
                                                int* __restrict__ ecnt, int* __restrict__ eoff,
                                                int* __restrict__ sn) {
  __shared__ int cnt_s[EPB], cur_s[EPB];
  int b = blockIdx.x, t = threadIdx.x;
  int lo = b * EPB, beg = b * ECAP2, end = gcure[b];
  if (t < EPB) cnt_s[t] = 0;
  __syncthreads();
  for (int i = beg + t; i < end; i += 256)
    atomicAdd(&cnt_s[(int)(buckE[i] >> 17) - lo], 1);
  __syncthreads();
  if (t < 64) {
    int v = (t < EPB) ? cnt_s[t] : 0;
    int inc = wave_incl_scan(v, t);
    if (t < EPB) cur_s[t] = beg + inc - v;
  }
  __syncthreads();
  if (t < EPB) {
    ecnt[lo + t] = cnt_s[t];
    eoff[lo + t] = cur_s[t];
  }
  __syncthreads();
  for (int i = beg + t; i < end; i += 256) {
    unsigned u = buckE[i];
    int key = (int)(u >> 17) - lo;
    int pos = atomicAdd(&cur_s[key], 1);
    sn[pos] = (int)(u & 0x1FFFF);
  }
}

// ---------------- fused: fine_N (blocks 0..199)  ||  k_edge (blocks 200..1449) ----------------
__global__ __launch_bounds__(256) void k_edge_fineN(const unsigned* __restrict__ buckN,
                                                    const int* __restrict__ gcurn,
                                                    int* __restrict__ ncnt, int* __restrict__ noff,
                                                    int* __restrict__ se,
                                                    const unsigned char* __restrict__ mji8,
                                                    const int* __restrict__ sn,
                                                    const int* __restrict__ eoff, const int* __restrict__ ecnt,
                                                    unsigned char* __restrict__ efeat8) {
  __shared__ int cnt_s[NPB], cur_s[NPB];
  int t = threadIdx.x;
  if (blockIdx.x < NB) {
    // ---- fine_N path ----
    int b = blockIdx.x;
    int lo = b * NPB, beg = b * ECAP2, end = gcurn[b];
    for (int i = t; i < NPB; i += 256) cnt_s[i] = 0;
    __syncthreads();
    for (int i = beg + t; i < end; i += 256)
      atomicAdd(&cnt_s[(int)(buckN[i] >> 14) - lo], 1);
    __syncthreads();
    if (t < 64) {
      int carry = beg;
#pragma unroll
      for (int base = 0; base < NPB; base += 64) {
        int idx = base + t;
        int v = (idx < NPB) ? cnt_s[idx] : 0;
        int inc = wave_incl_scan(v, t);
        if (idx < NPB) cur_s[idx] = carry + inc - v;
        carry += __shfl(inc, 63, 64);
      }
    }
    __syncthreads();
    for (int i = t; i < NPB; i += 256) {
      ncnt[lo + i] = cnt_s[i];
      noff[lo + i] = cur_s[i];
    }
    __syncthreads();
    for (int i = beg + t; i < end; i += 256) {
      unsigned u = buckN[i];
      int key = (int)(u >> 14) - lo;
      int pos = atomicAdd(&cur_s[key], 1);
      se[pos] = (int)(u & 0x3FFF);
    }
  } else {
    // ---- edge path ----
    int wave = (int)(blockIdx.x - NB) * 4 + (t >> 6);
    int lane = t & 63;
    int half = lane >> 5, sub2 = (lane >> 4) & 1, c4 = lane & 15;
    int edge = wave * 2 + half;
    if (edge >= N_EDGESC) return;
    int beg = eoff[edge], cnt = ecnt[edge];
    f32x2 a0 = {0.f, 0.f}, a1 = {0.f, 0.f}, a2 = {0.f, 0.f}, a3 = {0.f, 0.f};
#pragma unroll 4
    for (int p = sub2; p < cnt; p += 2) {
      int node = sn[beg + p];
      uint2 u = ((const uint2*)(mji8 + (size_t)node * FDIM))[c4];
      a0 += __builtin_amdgcn_cvt_pk_f32_fp8(u.x, false);
      a1 += __builtin_amdgcn_cvt_pk_f32_fp8(u.x, true);
      a2 += __builtin_amdgcn_cvt_pk_f32_fp8(u.y, false);
      a3 += __builtin_amdgcn_cvt_pk_f32_fp8(u.y, true);
    }
    a0[0] += __shfl_xor(a0[0], 16, 64); a0[1] += __shfl_xor(a0[1], 16, 64);
    a1[0] += __shfl_xor(a1[0], 16, 64); a1[1] += __shfl_xor(a1[1], 16, 64);
    a2[0] += __shfl_xor(a2[0], 16, 64); a2[1] += __shfl_xor(a2[1], 16, 64);
    a3[0] += __shfl_xor(a3[0], 16, 64); a3[1] += __shfl_xor(a3[1], 16, 64);
    if (sub2 == 0) {
      float inv = 1.0f / fmaxf((float)cnt, 1.0f);
      uint2 o;
      o.x = (unsigned)__builtin_amdgcn_cvt_pk_fp8_f32(a0[0] * inv, a0[1] * inv, 0, false);
      o.x = (unsigned)__builtin_amdgcn_cvt_pk_fp8_f32(a1[0] * inv, a1[1] * inv, (int)o.x, true);
      o.y = (unsigned)__builtin_amdgcn_cvt_pk_fp8_f32(a2[0] * inv, a2[1] * inv, 0, false);
      o.y = (unsigned)__builtin_amdgcn_cvt_pk_fp8_f32(a3[0] * inv, a3[1] * inv, (int)o.y, true);
      ((uint2*)(efeat8 + (size_t)edge * FDIM))[c4] = o;
    }
  }
}

// ---------------- node reduce: one node per 16-lane sub (4 nodes/wave) ----------------
__global__ __launch_bounds__(256) void k_node(const unsigned char* __restrict__ efeat8, const int* __restrict__ se,
                                              const int* __restrict__ noff, const int* __restrict__ ncnt,
                                              const float* __restrict__ recv, short* __restrict__ mi) {
  int wave = blockIdx.x * 4 + (threadIdx.x >> 6);
  int lane = threadIdx.x & 63;
  int sub = lane >> 4, c4 = lane & 15;
  int node = wave * 4 + sub;   // 25000 waves x 4 = 100000 exactly
  int beg = noff[node], cnt = ncnt[node];
  f32x2 a0 = {0.f, 0.f}, a1 = {0.f, 0.f}, a2 = {0.f, 0.f}, a3 = {0.f, 0.f};
#pragma unroll 4
  for (int p = 0; p < cnt; p++) {
    int e = se[beg + p];
    uint2 u = ((const uint2*)(efeat8 + (size_t)e * FDIM))[c4];
    a0 += __builtin_amdgcn_cvt_pk_f32_fp8(u.x, false);
    a1 += __builtin_amdgcn_cvt_pk_f32_fp8(u.x, true);
    a2 += __builtin_amdgcn_cvt_pk_f32_fp8(u.y, false);
    a3 += __builtin_amdgcn_cvt_pk_f32_fp8(u.y, true);
  }
  float s = recv[node] / fmaxf((float)cnt, 1.0f);
  u32x4 o;
  o[0] = pack2(a0[0] * s, a0[1] * s);
  o[1] = pack2(a1[0] * s, a1[1] * s);
  o[2] = pack2(a2[0] * s, a2[1] * s);
  o[3] = pack2(a3[0] * s, a3[1] * s);
  ((u32x4*)(mi + (size_t)node * FDIM))[c4] = o;
}

// ---------------- GEMM 2: out = gelu(x @ Wupd^T + b + m_i) -> f32, 32 rows/wave ----------------
__global__ __launch_bounds__(256) void k_gemm_upd(const float* __restrict__ x, const short* __restrict__ wb,
                                                  const float* __restrict__ bias, const short* __restrict__ mi,
                                                  float* __restrict__ out) {
  int gw = (blockIdx.x * 256 + threadIdx.x) >> 6;
  int lane = threadIdx.x & 63;
  if (gw >= N_NODESC / 32) return;
  int rb = gw * 32;
  int lr = lane & 15, lg = lane >> 4;

  bf16x8 A0[4], A1[4];
  const float* xrow0 = x + (size_t)(rb + lr) * FDIM + lg * 8;
  const float* xrow1 = xrow0 + 16 * FDIM;
#pragma unroll
  for (int kk = 0; kk < 4; kk++) {
    A0[kk] = ldA(xrow0 + kk * 32);
    A1[kk] = ldA(xrow1 + kk * 32);
  }

#pragma unroll
  for (int c = 0; c < 8; c++) {
    f32x4 acc0 = {0.f, 0.f, 0.f, 0.f}, acc1 = {0.f, 0.f, 0.f, 0.f};
    const short* wrow = wb + (size_t)(16 * c + lr) * FDIM + lg * 8;
#pragma unroll
    for (int kk = 0; kk < 4; kk++) {
      bf16x8 B = *(const bf16x8*)(wrow + kk * 32);
      acc0 = __builtin_amdgcn_mfma_f32_16x16x32_bf16(A0[kk], B, acc0, 0, 0, 0);
      acc1 = __builtin_amdgcn_mfma_f32_16x16x32_bf16(A1[kk], B, acc1, 0, 0, 0);
    }
    int col = 16 * c + lr;
    float bc = bias[col];
#pragma unroll
    for (int j = 0; j < 4; j++) {
      int row0 = rb + lg * 4 + j;
      float z0 = acc0[j] + bc + b2f(((const unsigned short*)mi)[(size_t)row0 * FDIM + col]);
      float z1 = acc1[j] + bc + b2f(((const unsigned short*)mi)[(size_t)(row0 + 16) * FDIM + col]);
      __builtin_nontemporal_store(gelu_fast(z0), &out[(size_t)row0 * FDIM + col]);
      __builtin_nontemporal_store(gelu_fast(z1), &out[(size_t)(row0 + 16) * FDIM + col]);
    }
  }
}

extern "C" void kernel_launch(void* const* d_in, const int* in_sizes, int n_in,
                              void* d_out, int out_size, void* d_ws, size_t ws_size,
                              hipStream_t stream) {
  const float* x = (const float*)d_in[0];
  const float* action = (const float*)d_in[1];
  const float* wmsg = (const float*)d_in[2];
  const float* wupd = (const float*)d_in[3];
  const float* bupd = (const float*)d_in[4];
  const int* pn = (const int*)d_in[5];
  const int* pe = (const int*)d_in[6];
  float* out = (float*)d_out;

  char* p = (char*)d_ws;
  auto alloc = [&](size_t bytes) -> char* {
    char* r = p;
    p += (bytes + 255) & ~(size_t)255;
    return r;
  };
  unsigned char* mji8 = (unsigned char*)alloc((size_t)N_NODESC * FDIM);
  short* mi = (short*)alloc((size_t)N_NODESC * FDIM * 2);   // also hosts buckE+buckN (consumed before k_node writes mi)
  unsigned char* efeat8 = (unsigned char*)alloc((size_t)N_EDGESC * FDIM);
  int* sn = (int*)alloc((size_t)NB * ECAP2 * 4);
  int* se = (int*)alloc((size_t)NB * ECAP2 * 4);
  short* wmsgb = (short*)alloc(FDIM * FDIM * 2);
  short* wupdb = (short*)alloc(FDIM * FDIM * 2);
  float* send = (float*)alloc(N_NODESC * 4);
  float* recv = (float*)alloc(N_NODESC * 4);
  int* ecnt = (int*)alloc(N_EDGESC * 4);
  int* eoff = (int*)alloc(N_EDGESC * 4);
  int* ncnt = (int*)alloc(N_NODESC * 4);
  int* noff = (int*)alloc(N_NODESC * 4);
  int* gcure = (int*)alloc(NB * 4);
  int* gcurn = (int*)alloc(NB * 4);

  unsigned* buckE = (unsigned*)mi;                               // 6.96 MB
  unsigned* buckN = buckE + (size_t)NB * ECAP2;                  // 6.96 MB (fits mi's 25.6 MB region)

  k_prep<<<391, 256, 0, stream>>>(action, wmsg, wupd, wmsgb, wupdb, send, recv, gcure, gcurn);
  k_part_msg<<<PA_NCH + MSG_BLKS, 256, 0, stream>>>(pn, pe, gcure, gcurn, buckE, buckN,
                                                    x, wmsgb, send, mji8);
  k_fine_e<<<NB, 256, 0, stream>>>(buckE, gcure, ecnt, eoff, sn);
  k_edge_fineN<<<NB + 1250, 256, 0, stream>>>(buckN, gcurn, ncnt, noff, se,
                                              mji8, sn, eoff, ecnt, efeat8);
  k_node<<<6250, 256, 0, stream>>>(efeat8, se, noff, ncnt, recv, mi);
  k_gemm_upd<<<782, 256, 0, stream>>>(x, wupdb, bupd, mi, out);
}

// Round 15
// 164.414 us; speedup vs baseline: 1.8855x; 1.0674x over previous
//
#include <hip/hip_runtime.h>

#define N_NODESC 100000
#define N_EDGESC 10000
#define N_PAIRSC 1600000
#define FDIM 128

#define NB 200       // buckets per path
#define EPB 50       // edges per bucket  (200*50 = 10000)
#define NPB 500      // nodes per bucket  (200*500 = 100000)
#define ECAP2 8704   // fixed bucket stride; mean 8000, sigma 89 -> 7.9 sigma slack
#define PA_CHUNK 8192
#define PA_NCH ((N_PAIRSC + PA_CHUNK - 1) / PA_CHUNK)  // 196
#define MSG_BLKS 782

typedef short bf16x8 __attribute__((ext_vector_type(8)));
typedef float f32x4 __attribute__((ext_vector_type(4)));
typedef float f32x2 __attribute__((ext_vector_type(2)));
typedef int i32x4 __attribute__((ext_vector_type(4)));
typedef unsigned u32x4 __attribute__((ext_vector_type(4)));

__device__ __forceinline__ unsigned short f2b(float f) {
  unsigned u = __float_as_uint(f);
  u += 0x7fffu + ((u >> 16) & 1u);
  return (unsigned short)(u >> 16);
}
__device__ __forceinline__ float b2f(unsigned short b) {
  return __uint_as_float(((unsigned)b) << 16);
}
__device__ __forceinline__ unsigned pack2(float a, float b) {
  return (unsigned)f2b(a) | ((unsigned)f2b(b) << 16);
}
// tanh-form gelu: z*e/(e+1), e=exp(1.59576912*z*(1+0.044715 z^2)). |diff| <= ~1e-3.
__device__ __forceinline__ float gelu_fast(float z) {
  float z2 = z * z;
  float w = fmaf(0.044715f, z2, 1.0f);
  float e = __expf(1.5957691216f * z * w);
  return z * e * __builtin_amdgcn_rcpf(e + 1.0f);
}
// load 8 consecutive f32 from row, convert to bf16x8 fragment
__device__ __forceinline__ bf16x8 ldA(const float* p) {
  float4 u0 = *(const float4*)p;
  float4 u1 = *(const float4*)(p + 4);
  u32x4 w = {pack2(u0.x, u0.y), pack2(u0.z, u0.w), pack2(u1.x, u1.y), pack2(u1.z, u1.w)};
  return __builtin_bit_cast(bf16x8, w);
}

// ---------------- prep: weights -> bf16, send/recv, bucket cursor init ----------------
__global__ __launch_bounds__(256) void k_prep(const float* __restrict__ action,
                                              const float* __restrict__ wmsg, const float* __restrict__ wupd,
                                              short* __restrict__ wmsgb, short* __restrict__ wupdb,
                                              float* __restrict__ send, float* __restrict__ recv,
                                              int* __restrict__ gcure, int* __restrict__ gcurn) {
  int i = blockIdx.x * 256 + threadIdx.x;
  if (i < FDIM * FDIM) {
    wmsgb[i] = (short)f2b(wmsg[i]);
    wupdb[i] = (short)f2b(wupd[i]);
  }
  if (i < N_NODESC) {
    float a0 = action[i * 3 + 0], a1 = action[i * 3 + 1], a2 = action[i * 3 + 2];
    send[i] = a0 + a2;
    recv[i] = a0 + a1;
  }
  if (i < NB) {
    gcure[i] = i * ECAP2;
    gcurn[i] = i * ECAP2;
  }
}

// ---------------- scan helper ----------------
__device__ __forceinline__ int wave_incl_scan(int v, int lane) {
#pragma unroll
  for (int d = 1; d < 64; d <<= 1) {
    int n = __shfl_up(v, d, 64);
    if (lane >= d) v += n;
  }
  return v;
}

// ---------------- fused: single-pass k_part (blocks 0..195)  ||  k_gemm_msg (196..977) ----------------
__global__ __launch_bounds__(256) void k_part_msg(const int* __restrict__ pn, const int* __restrict__ pe,
                                                  int* __restrict__ gcure, int* __restrict__ gcurn,
                                                  unsigned* __restrict__ buckE, unsigned* __restrict__ buckN,
                                                  const float* __restrict__ x, const short* __restrict__ wb,
                                                  const float* __restrict__ send,
                                                  unsigned char* __restrict__ mji8) {
  __shared__ unsigned stage[PA_CHUNK];   // 32 KB item staging (E-packed; N-word derived)
  __shared__ int ce[NB], cn[NB];
  int t = threadIdx.x;
  if (blockIdx.x < PA_NCH) {
    // ---- partition path: single global pass, stage in LDS ----
    for (int i = t; i < NB; i += 256) { ce[i] = 0; cn[i] = 0; }
    __syncthreads();
    long long base = (long long)blockIdx.x * PA_CHUNK;
    int nItems = (int)(((long long)N_PAIRSC - base) < PA_CHUNK ? (N_PAIRSC - base) : PA_CHUNK);
    for (int q = t; q < PA_CHUNK / 4; q += 256) {
      long long idx = base + (long long)q * 4;
      if (idx >= N_PAIRSC) break;
      i32x4 e4 = __builtin_nontemporal_load((const i32x4*)(pe + idx));
      i32x4 v4 = __builtin_nontemporal_load((const i32x4*)(pn + idx));
#pragma unroll
      for (int j = 0; j < 4; j++) {
        unsigned ee = (unsigned)e4[j], vv = (unsigned)v4[j];
        stage[q + j * (PA_CHUNK / 4)] = (ee << 17) | vv;  // stride-1 per lane: conflict-free
        atomicAdd(&ce[ee / EPB], 1);
        atomicAdd(&cn[vv / NPB], 1);
      }
    }
    __syncthreads();
    for (int i = t; i < NB; i += 256) {
      ce[i] = atomicAdd(&gcure[i], ce[i]);
      cn[i] = atomicAdd(&gcurn[i], cn[i]);
    }
    __syncthreads();
    // scatter from LDS (item order is irrelevant; only key grouping matters downstream)
    for (int i = t; i < PA_CHUNK; i += 256) {
      int q = i & (PA_CHUNK / 4 - 1), j = i >> 11;   // inverse of stage layout
      long long idx = base + (long long)q * 4 + j;
      if (idx >= N_PAIRSC) continue;
      unsigned u = stage[i];
      unsigned ee = u >> 17, vv = u & 0x1FFFF;
      int p1 = atomicAdd(&ce[ee / EPB], 1);
      buckE[p1] = u;                        // edge key (14b) | node val (17b)
      int p2 = atomicAdd(&cn[vv / NPB], 1);
      buckN[p2] = (vv << 14) | ee;          // node key (17b) | edge val (14b)
    }
    (void)nItems;
  } else {
    // ---- gemm_msg path ----
    int gw = ((int)(blockIdx.x - PA_NCH) * 256 + t) >> 6;
    int lane = t & 63;
    if (gw >= N_NODESC / 32) return;
    int rb = gw * 32;
    int lr = lane & 15, lg = lane >> 4;

    bf16x8 A0[4], A1[4];
    const float* xrow0 = x + (size_t)(rb + lr) * FDIM + lg * 8;
    const float* xrow1 = xrow0 + 16 * FDIM;
#pragma unroll
    for (int kk = 0; kk < 4; kk++) {
      A0[kk] = ldA(xrow0 + kk * 32);
      A1[kk] = ldA(xrow1 + kk * 32);
    }
    float sv0[4], sv1[4];
#pragma unroll
    for (int j = 0; j < 4; j++) {
      sv0[j] = send[rb + lg * 4 + j];
      sv1[j] = send[rb + 16 + lg * 4 + j];
    }
#pragma unroll
    for (int c = 0; c < 8; c++) {
      f32x4 acc0 = {0.f, 0.f, 0.f, 0.f}, acc1 = {0.f, 0.f, 0.f, 0.f};
      const short* wrow = wb + (size_t)(16 * c + lr) * FDIM + lg * 8;
#pragma unroll
      for (int kk = 0; kk < 4; kk++) {
        bf16x8 B = *(const bf16x8*)(wrow + kk * 32);
        acc0 = __builtin_amdgcn_mfma_f32_16x16x32_bf16(A0[kk], B, acc0, 0, 0, 0);
        acc1 = __builtin_amdgcn_mfma_f32_16x16x32_bf16(A1[kk], B, acc1, 0, 0, 0);
      }
      int col = 16 * c + lr;
#pragma unroll
      for (int j = 0; j < 4; j++) {
        float m0 = gelu_fast(acc0[j]) * sv0[j];
        float m1 = gelu_fast(acc1[j]) * sv1[j];
        int row0 = rb + lg * 4 + j;
        mji8[(size_t)row0 * FDIM + col] =
            (unsigned char)(__builtin_amdgcn_cvt_pk_fp8_f32(m0, m0, 0, false) & 0xFF);
        mji8[(size_t)(row0 + 16) * FDIM + col] =
            (unsigned char)(__builtin_amdgcn_cvt_pk_fp8_f32(m1, m1, 0, false) & 0xFF);
      }
    }
  }
}

// ---------------- fine_E: per-edge counts/offsets + sorted sn ----------------
__global__ __launch_bounds__(256) void k_fine_e(const unsigned* __restrict__ buckE,
                                                const int* __restrict__ gcure,
                                                int* __restrict__ ecnt, int* __restrict__ eoff,
                                                int* __restrict__ sn) {
  __shared__ int cnt_s[EPB], cur_s[EPB];
  int b = blockIdx.x, t = threadIdx.x;
  int lo = b * EPB, beg = b * ECAP2, end = gcure[b];
  if (t < EPB) cnt_s[t] = 0;
  __syncthreads();
  for (int i = beg + t; i < end; i += 256)
    atomicAdd(&cnt_s[(int)(buckE[i] >> 17) - lo], 1);
  __syncthreads();
  if (t < 64) {
    int v = (t < EPB) ? cnt_s[t] : 0;
    int inc = wave_incl_scan(v, t);
    if (t < EPB) cur_s[t] = beg + inc - v;
  }
  __syncthreads();
  if (t < EPB) {
    ecnt[lo + t] = cnt_s[t];
    eoff[lo + t] = cur_s[t];
  }
  __syncthreads();
  for (int i = beg + t; i < end; i += 256) {
    unsigned u = buckE[i];
    int key = (int)(u >> 17) - lo;
    int pos = atomicAdd(&cur_s[key], 1);
    sn[pos] = (int)(u & 0x1FFFF);
  }
}

// ---------------- fused: fine_N (blocks 0..199)  ||  k_edge (blocks 200..1449) ----------------
__global__ __launch_bounds__(256) void k_edge_fineN(const unsigned* __restrict__ buckN,
                                                    const int* __restrict__ gcurn,
                                                    int* __restrict__ ncnt, int* __restrict__ noff,
                                                    int* __restrict__ se,
                                                    const unsigned char* __restrict__ mji8,
                                                    const int* __restrict__ sn,
                                                    const int* __restrict__ eoff, const int* __restrict__ ecnt,
                                                    unsigned char* __restrict__ efeat8) {
  __shared__ int cnt_s[NPB], cur_s[NPB];
  int t = threadIdx.x;
  if (blockIdx.x < NB) {
    // ---- fine_N path ----
    int b = blockIdx.x;
    int lo = b * NPB, beg = b * ECAP2, end = gcurn[b];
    for (int i = t; i < NPB; i += 256) cnt_s[i] = 0;
    __syncthreads();
    for (int i = beg + t; i < end; i += 256)
      atomicAdd(&cnt_s[(int)(buckN[i] >> 14) - lo], 1);
    __syncthreads();
    if (t < 64) {
      int carry = beg;
#pragma unroll
      for (int base = 0; base < NPB; base += 64) {
        int idx = base + t;
        int v = (idx < NPB) ? cnt_s[idx] : 0;
        int inc = wave_incl_scan(v, t);
        if (idx < NPB) cur_s[idx] = carry + inc - v;
        carry += __shfl(inc, 63, 64);
      }
    }
    __syncthreads();
    for (int i = t; i < NPB; i += 256) {
      ncnt[lo + i] = cnt_s[i];
      noff[lo + i] = cur_s[i];
    }
    __syncthreads();
    for (int i = beg + t; i < end; i += 256) {
      unsigned u = buckN[i];
      int key = (int)(u >> 14) - lo;
      int pos = atomicAdd(&cur_s[key], 1);
      se[pos] = (int)(u & 0x3FFF);
    }
  } else {
    // ---- edge path ----
    int wave = (int)(blockIdx.x - NB) * 4 + (t >> 6);
    int lane = t & 63;
    int half = lane >> 5, sub2 = (lane >> 4) & 1, c4 = lane & 15;
    int edge = wave * 2 + half;
    if (edge >= N_EDGESC) return;
    int beg = eoff[edge], cnt = ecnt[edge];
    f32x2 a0 = {0.f, 0.f}, a1 = {0.f, 0.f}, a2 = {0.f, 0.f}, a3 = {0.f, 0.f};
#pragma unroll 4
    for (int p = sub2; p < cnt; p += 2) {
      int node = sn[beg + p];
      uint2 u = ((const uint2*)(mji8 + (size_t)node * FDIM))[c4];
      a0 += __builtin_amdgcn_cvt_pk_f32_fp8(u.x, false);
      a1 += __builtin_amdgcn_cvt_pk_f32_fp8(u.x, true);
      a2 += __builtin_amdgcn_cvt_pk_f32_fp8(u.y, false);
      a3 += __builtin_amdgcn_cvt_pk_f32_fp8(u.y, true);
    }
    a0[0] += __shfl_xor(a0[0], 16, 64); a0[1] += __shfl_xor(a0[1], 16, 64);
    a1[0] += __shfl_xor(a1[0], 16, 64); a1[1] += __shfl_xor(a1[1], 16, 64);
    a2[0] += __shfl_xor(a2[0], 16, 64); a2[1] += __shfl_xor(a2[1], 16, 64);
    a3[0] += __shfl_xor(a3[0], 16, 64); a3[1] += __shfl_xor(a3[1], 16, 64);
    if (sub2 == 0) {
      float inv = 1.0f / fmaxf((float)cnt, 1.0f);
      uint2 o;
      o.x = (unsigned)__builtin_amdgcn_cvt_pk_fp8_f32(a0[0] * inv, a0[1] * inv, 0, false);
      o.x = (unsigned)__builtin_amdgcn_cvt_pk_fp8_f32(a1[0] * inv, a1[1] * inv, (int)o.x, true);
      o.y = (unsigned)__builtin_amdgcn_cvt_pk_fp8_f32(a2[0] * inv, a2[1] * inv, 0, false);
      o.y = (unsigned)__builtin_amdgcn_cvt_pk_fp8_f32(a3[0] * inv, a3[1] * inv, (int)o.y, true);
      ((uint2*)(efeat8 + (size_t)edge * FDIM))[c4] = o;
    }
  }
}

// ---------------- node reduce: one node per 16-lane sub (4 nodes/wave) ----------------
__global__ __launch_bounds__(256) void k_node(const unsigned char* __restrict__ efeat8, const int* __restrict__ se,
                                              const int* __restrict__ noff, const int* __restrict__ ncnt,
                                              const float* __restrict__ recv, short* __restrict__ mi) {
  int wave = blockIdx.x * 4 + (threadIdx.x >> 6);
  int lane = threadIdx.x & 63;
  int sub = lane >> 4, c4 = lane & 15;
  int node = wave * 4 + sub;   // 25000 waves x 4 = 100000 exactly
  int beg = noff[node], cnt = ncnt[node];
  f32x2 a0 = {0.f, 0.f}, a1 = {0.f, 0.f}, a2 = {0.f, 0.f}, a3 = {0.f, 0.f};
#pragma unroll 4
  for (int p = 0; p < cnt; p++) {
    int e = se[beg + p];
    uint2 u = ((const uint2*)(efeat8 + (size_t)e * FDIM))[c4];
    a0 += __builtin_amdgcn_cvt_pk_f32_fp8(u.x, false);
    a1 += __builtin_amdgcn_cvt_pk_f32_fp8(u.x, true);
    a2 += __builtin_amdgcn_cvt_pk_f32_fp8(u.y, false);
    a3 += __builtin_amdgcn_cvt_pk_f32_fp8(u.y, true);
  }
  float s = recv[node] / fmaxf((float)cnt, 1.0f);
  u32x4 o;
  o[0] = pack2(a0[0] * s, a0[1] * s);
  o[1] = pack2(a1[0] * s, a1[1] * s);
  o[2] = pack2(a2[0] * s, a2[1] * s);
  o[3] = pack2(a3[0] * s, a3[1] * s);
  ((u32x4*)(mi + (size_t)node * FDIM))[c4] = o;
}

// ---------------- GEMM 2: out = gelu(x @ Wupd^T + b + m_i) -> f32, 32 rows/wave ----------------
__global__ __launch_bounds__(256) void k_gemm_upd(const float* __restrict__ x, const short* __restrict__ wb,
                                                  const float* __restrict__ bias, const short* __restrict__ mi,
                                                  float* __restrict__ out) {
  int gw = (blockIdx.x * 256 + threadIdx.x) >> 6;
  int lane = threadIdx.x & 63;
  if (gw >= N_NODESC / 32) return;
  int rb = gw * 32;
  int lr = lane & 15, lg = lane >> 4;

  bf16x8 A0[4], A1[4];
  const float* xrow0 = x + (size_t)(rb + lr) * FDIM + lg * 8;
  const float* xrow1 = xrow0 + 16 * FDIM;
#pragma unroll
  for (int kk = 0; kk < 4; kk++) {
    A0[kk] = ldA(xrow0 + kk * 32);
    A1[kk] = ldA(xrow1 + kk * 32);
  }

#pragma unroll
  for (int c = 0; c < 8; c++) {
    f32x4 acc0 = {0.f, 0.f, 0.f, 0.f}, acc1 = {0.f, 0.f, 0.f, 0.f};
    const short* wrow = wb + (size_t)(16 * c + lr) * FDIM + lg * 8;
#pragma unroll
    for (int kk = 0; kk < 4; kk++) {
      bf16x8 B = *(const bf16x8*)(wrow + kk * 32);
      acc0 = __builtin_amdgcn_mfma_f32_16x16x32_bf16(A0[kk], B, acc0, 0, 0, 0);
      acc1 = __builtin_amdgcn_mfma_f32_16x16x32_bf16(A1[kk], B, acc1, 0, 0, 0);
    }
    int col = 16 * c + lr;
    float bc = bias[col];
#pragma unroll
    for (int j = 0; j < 4; j++) {
      int row0 = rb + lg * 4 + j;
      float z0 = acc0[j] + bc + b2f(((const unsigned short*)mi)[(size_t)row0 * FDIM + col]);
      float z1 = acc1[j] + bc + b2f(((const unsigned short*)mi)[(size_t)(row0 + 16) * FDIM + col]);
      __builtin_nontemporal_store(gelu_fast(z0), &out[(size_t)row0 * FDIM + col]);
      __builtin_nontemporal_store(gelu_fast(z1), &out[(size_t)(row0 + 16) * FDIM + col]);
    }
  }
}

extern "C" void kernel_launch(void* const* d_in, const int* in_sizes, int n_in,
                              void* d_out, int out_size, void* d_ws, size_t ws_size,
                              hipStream_t stream) {
  const float* x = (const float*)d_in[0];
  const float* action = (const float*)d_in[1];
  const float* wmsg = (const float*)d_in[2];
  const float* wupd = (const float*)d_in[3];
  const float* bupd = (const float*)d_in[4];
  const int* pn = (const int*)d_in[5];
  const int* pe = (const int*)d_in[6];
  float* out = (float*)d_out;

  char* p = (char*)d_ws;
  auto alloc = [&](size_t bytes) -> char* {
    char* r = p;
    p += (bytes + 255) & ~(size_t)255;
    return r;
  };
  unsigned char* mji8 = (unsigned char*)alloc((size_t)N_NODESC * FDIM);
  short* mi = (short*)alloc((size_t)N_NODESC * FDIM * 2);   // also hosts buckE+buckN (consumed before k_node writes mi)
  unsigned char* efeat8 = (unsigned char*)alloc((size_t)N_EDGESC * FDIM);
  int* sn = (int*)alloc((size_t)NB * ECAP2 * 4);
  int* se = (int*)alloc((size_t)NB * ECAP2 * 4);
  short* wmsgb = (short*)alloc(FDIM * FDIM * 2);
  short* wupdb = (short*)alloc(FDIM * FDIM * 2);
  float* send = (float*)alloc(N_NODESC * 4);
  float* recv = (float*)alloc(N_NODESC * 4);
  int* ecnt = (int*)alloc(N_EDGESC * 4);
  int* eoff = (int*)alloc(N_EDGESC * 4);
  int* ncnt = (int*)alloc(N_NODESC * 4);
  int* noff = (int*)alloc(N_NODESC * 4);
  int* gcure = (int*)alloc(NB * 4);
  int* gcurn = (int*)alloc(NB * 4);

  unsigned* buckE = (unsigned*)mi;                               // 6.96 MB
  unsigned* buckN = buckE + (size_t)NB * ECAP2;                  // 6.96 MB (fits mi's 25.6 MB region)

  k_prep<<<391, 256, 0, stream>>>(action, wmsg, wupd, wmsgb, wupdb, send, recv, gcure, gcurn);
  k_part_msg<<<PA_NCH + MSG_BLKS, 256, 0, stream>>>(pn, pe, gcure, gcurn, buckE, buckN,
                                                    x, wmsgb, send, mji8);
  k_fine_e<<<NB, 256, 0, stream>>>(buckE, gcure, ecnt, eoff, sn);
  k_edge_fineN<<<NB + 1250, 256, 0, stream>>>(buckN, gcurn, ncnt, noff, se,
                                              mji8, sn, eoff, ecnt, efeat8);
  k_node<<<6250, 256, 0, stream>>>(efeat8, se, noff, ncnt, recv, mi);
  k_gemm_upd<<<782, 256, 0, stream>>>(x, wupdb, bupd, mi, out);
}